// Round 1
// baseline (858.492 us; speedup 1.0000x reference)
//
#include <hip/hip_runtime.h>

#define B_SZ 8
#define L_SZ 4096
#define H_SZ 512
#define P_SZ 512
#define M_SZ (B_SZ * L_SZ)      // 32768
#define NCH 32
#define CHUNK (L_SZ / NCH)      // 128
#define PH (P_SZ * H_SZ)
#define MH ((size_t)M_SZ * H_SZ)
#define MP ((size_t)M_SZ * P_SZ)

typedef __attribute__((ext_vector_type(8))) __bf16 bf16x8;
typedef __attribute__((ext_vector_type(4))) float f32x4;

// RNE fp32 -> bf16 split: x ~= hi + lo, each bf16. Error ~2^-18 relative.
__device__ __forceinline__ void splitf(float x, unsigned short& h, unsigned short& l) {
    unsigned u = __float_as_uint(x);
    unsigned hr = (u + 0x7fffu + ((u >> 16) & 1u)) >> 16;
    h = (unsigned short)hr;
    float lo = x - __uint_as_float(hr << 16);       // exact (Sterbenz)
    unsigned ul = __float_as_uint(lo);
    l = (unsigned short)((ul + 0x7fffu + ((ul >> 16) & 1u)) >> 16);
}

__device__ __forceinline__ float b2f(unsigned short s) {
    return __uint_as_float(((unsigned)s) << 16);
}

__global__ void precompute_k(const float* __restrict__ lam_re,
                             const float* __restrict__ lam_im,
                             const float* __restrict__ log_step,
                             float2* __restrict__ Lbar,
                             float2* __restrict__ AS,
                             float2* __restrict__ scale) {
    int p = blockIdx.x * blockDim.x + threadIdx.x;
    if (p >= P_SZ) return;
    float lr = lam_re[p], li = lam_im[p];
    float dt = expf(log_step[p]);
    float zr = lr * dt, zi = li * dt;
    float er = expf(zr);
    float ar = er * cosf(zi), ai = er * sinf(zi);
    Lbar[p] = make_float2(ar, ai);
    float nr = ar - 1.0f, ni = ai;
    float d2 = lr * lr + li * li;
    scale[p] = make_float2((nr * lr + ni * li) / d2, (ni * lr - nr * li) / d2);
    float xr = ar, xi = ai;
    #pragma unroll
    for (int i = 0; i < 7; i++) {      // A^128 via squarings
        float tr = xr * xr - xi * xi;
        float ti = 2.0f * xr * xi;
        xr = tr; xi = ti;
    }
    AS[p] = make_float2(xr, xi);
}

// PpowS[r][p] = Lbar[p]^(8r+1), r in [0,16)  (64 KB, stays L2-hot)
__global__ void ppows_k(const float2* __restrict__ Lbar,
                        float2* __restrict__ PpowS) {
    int idx = blockIdx.x * blockDim.x + threadIdx.x;   // r*P + p
    if (idx >= 16 * P_SZ) return;
    int p = idx & (P_SZ - 1);
    int r = idx >> 9;
    int e = 8 * r + 1;                                  // 1..121
    float2 base = Lbar[p];
    float rr = 1.0f, ri = 0.0f;
    float br = base.x, bi = base.y;
    #pragma unroll
    for (int bit = 0; bit < 7; bit++) {
        if ((e >> bit) & 1) {
            float nr = rr * br - ri * bi;
            float ni = rr * bi + ri * br;
            rr = nr; ri = ni;
        }
        float sr = br * br - bi * bi;
        float si = 2.0f * br * bi;
        br = sr; bi = si;
    }
    PpowS[idx] = make_float2(rr, ri);
}

// B_bar = scale * (Bre + i Bim), split into 4 bf16 planes [wre_h|wre_l|wim_h|wim_l]
__global__ void bbar_k(const float* __restrict__ Bre,
                       const float* __restrict__ Bim,
                       const float2* __restrict__ scale,
                       unsigned short* __restrict__ Wpl) {
    int idx = blockIdx.x * blockDim.x + threadIdx.x;
    if (idx >= PH) return;
    int p = idx / H_SZ;
    float2 s = scale[p];
    float br = Bre[idx], bi = Bim[idx];
    float wr = s.x * br - s.y * bi;
    float wi = s.x * bi + s.y * br;
    unsigned short h, l;
    splitf(wr, h, l);
    Wpl[idx] = h; Wpl[PH + idx] = l;
    splitf(wi, h, l);
    Wpl[2 * PH + idx] = h; Wpl[3 * PH + idx] = l;
}

// C planes: [cre_h|cre_l|cimn_h|cimn_l] where cimn = -Cim
__global__ void csplit_k(const float* __restrict__ Cre,
                         const float* __restrict__ Cim,
                         unsigned short* __restrict__ Cpl) {
    int idx = blockIdx.x * blockDim.x + threadIdx.x;
    if (idx >= PH) return;
    unsigned short h, l;
    splitf(Cre[idx], h, l);
    Cpl[idx] = h; Cpl[PH + idx] = l;
    splitf(-Cim[idx], h, l);
    Cpl[2 * PH + idx] = h; Cpl[3 * PH + idx] = l;
}

// U -> 2 bf16 planes [uh|ul], done ONCE (the old in-gemm1 split was 8x redundant)
__global__ __launch_bounds__(256) void usplit_k(const float* __restrict__ U,
                                                unsigned short* __restrict__ Upl) {
    size_t i4 = (size_t)blockIdx.x * 256 + threadIdx.x;
    float4 v = *(const float4*)&U[i4 * 4];
    ushort4 h, l;
    splitf(v.x, h.x, l.x);
    splitf(v.y, h.y, l.y);
    splitf(v.z, h.z, l.z);
    splitf(v.w, h.w, l.w);
    *(ushort4*)&Upl[i4 * 4] = h;
    *(ushort4*)&Upl[MH + i4 * 4] = l;
}

// swizzle: id = (m&7) + n*8 + (m>>3)*64  ->  same-m blocks share an XCD AND
// are within a 64-id dispatch window (co-resident => L2 temporal locality).
__device__ __forceinline__ void deswizzle(int bid, int& m, int& n) {
    int xcd = bid & 7;
    n = (bid >> 3) & 7;
    m = ((bid >> 6) << 3) + xcd;
}

// GEMM1: pure plane-copy staging (no in-loop splitf), fused LOCAL scan over the
// 128-row chunk (zero carry-in). Epilogue writes the local scan as 4 bf16
// planes Xpl[rh|rl|ih|il] (same bytes as the old float2 Bu).
__global__ __launch_bounds__(256) void gemm1_k(const unsigned short* __restrict__ Upl,
                                               const unsigned short* __restrict__ Wpl,
                                               const float2* __restrict__ Lbar,
                                               unsigned short* __restrict__ Xpl,
                                               float2* __restrict__ carries) {
    __shared__ __align__(16) char smem[65536];
    unsigned short* sUh = (unsigned short*)smem;        // 8KB
    unsigned short* sUl = sUh + 128 * 32;               // 8KB
    unsigned short* sW  = sUl + 128 * 32;               // 16KB
    const int tid = threadIdx.x;
    int g, nb;
    deswizzle(blockIdx.x, g, nb);
    const int m0 = g * 128;
    const int n0 = nb * 64;
    const int lane = tid & 63, wv = tid >> 6;
    const int wm = wv & 1, wn = wv >> 1;
    const int lr = lane & 15, kg = lane >> 4;

    f32x4 accr[4][2], acci[4][2];
    #pragma unroll
    for (int i = 0; i < 4; i++)
        #pragma unroll
        for (int j = 0; j < 2; j++) { accr[i][j] = (f32x4)0.0f; acci[i][j] = (f32x4)0.0f; }

    const int srow = tid >> 2, sc8 = tid & 3;

    int4 ust[4];
    int4 wst[4];
    #pragma unroll
    for (int q = 0; q < 4; q++)
        ust[q] = *(const int4*)&Upl[(size_t)(q >> 1) * MH + (size_t)(m0 + (q & 1) * 64 + srow) * H_SZ + sc8 * 8];
    #pragma unroll
    for (int q = 0; q < 4; q++)
        wst[q] = *(const int4*)&Wpl[(size_t)q * PH + (size_t)(n0 + srow) * H_SZ + sc8 * 8];

    for (int k0 = 0; k0 < H_SZ; k0 += 32) {
        __syncthreads();
        #pragma unroll
        for (int q = 0; q < 4; q++) {
            unsigned short* dst = (q >> 1) ? sUl : sUh;
            *(int4*)&dst[((q & 1) * 64 + srow) * 32 + sc8 * 8] = ust[q];
        }
        #pragma unroll
        for (int q = 0; q < 4; q++)
            *(int4*)&sW[q * 2048 + srow * 32 + sc8 * 8] = wst[q];
        __syncthreads();
        if (k0 + 32 < H_SZ) {
            #pragma unroll
            for (int q = 0; q < 4; q++)
                ust[q] = *(const int4*)&Upl[(size_t)(q >> 1) * MH + (size_t)(m0 + (q & 1) * 64 + srow) * H_SZ + k0 + 32 + sc8 * 8];
            #pragma unroll
            for (int q = 0; q < 4; q++)
                wst[q] = *(const int4*)&Wpl[(size_t)q * PH + (size_t)(n0 + srow) * H_SZ + k0 + 32 + sc8 * 8];
        }

        bf16x8 uh[4], ul[4];
        #pragma unroll
        for (int mi = 0; mi < 4; mi++) {
            int off = (wm * 64 + mi * 16 + lr) * 32 + kg * 8;
            uh[mi] = *(const bf16x8*)&sUh[off];
            ul[mi] = *(const bf16x8*)&sUl[off];
        }
        bf16x8 wrh[2], wrl[2], wih[2], wil[2];
        #pragma unroll
        for (int nj = 0; nj < 2; nj++) {
            int off = (wn * 32 + nj * 16 + lr) * 32 + kg * 8;
            wrh[nj] = *(const bf16x8*)&sW[0 * 2048 + off];
            wrl[nj] = *(const bf16x8*)&sW[1 * 2048 + off];
            wih[nj] = *(const bf16x8*)&sW[2 * 2048 + off];
            wil[nj] = *(const bf16x8*)&sW[3 * 2048 + off];
        }
        #pragma unroll
        for (int mi = 0; mi < 4; mi++)
            #pragma unroll
            for (int nj = 0; nj < 2; nj++) {
                accr[mi][nj] = __builtin_amdgcn_mfma_f32_16x16x32_bf16(uh[mi], wrh[nj], accr[mi][nj], 0, 0, 0);
                accr[mi][nj] = __builtin_amdgcn_mfma_f32_16x16x32_bf16(uh[mi], wrl[nj], accr[mi][nj], 0, 0, 0);
                accr[mi][nj] = __builtin_amdgcn_mfma_f32_16x16x32_bf16(ul[mi], wrh[nj], accr[mi][nj], 0, 0, 0);
                acci[mi][nj] = __builtin_amdgcn_mfma_f32_16x16x32_bf16(uh[mi], wih[nj], acci[mi][nj], 0, 0, 0);
                acci[mi][nj] = __builtin_amdgcn_mfma_f32_16x16x32_bf16(uh[mi], wil[nj], acci[mi][nj], 0, 0, 0);
                acci[mi][nj] = __builtin_amdgcn_mfma_f32_16x16x32_bf16(ul[mi], wih[nj], acci[mi][nj], 0, 0, 0);
            }
    }

    // ---- epilogue: local chunk scan in LDS (reuses staging LDS) ----
    __syncthreads();
    float2* xs = (float2*)smem;                // [128 t][64 p] = 64KB
    #pragma unroll
    for (int mi = 0; mi < 4; mi++)
        #pragma unroll
        for (int nj = 0; nj < 2; nj++)
            #pragma unroll
            for (int r = 0; r < 4; r++) {
                int t = wm * 64 + mi * 16 + kg * 4 + r;
                int p = wn * 32 + nj * 16 + lr;
                xs[t * 64 + p] = make_float2(accr[mi][nj][r], acci[mi][nj][r]);
            }
    __syncthreads();
    if (tid < 64) {
        float2 A = Lbar[n0 + tid];
        float xr = 0.f, xi = 0.f;
        for (int t = 0; t < CHUNK; t++) {
            float2 v = xs[t * 64 + tid];
            float nr = fmaf(A.x, xr, fmaf(-A.y, xi, v.x));
            float ni = fmaf(A.x, xi, fmaf(A.y, xr, v.y));
            xr = nr; xi = ni;
            xs[t * 64 + tid] = make_float2(xr, xi);
        }
        carries[(size_t)g * P_SZ + n0 + tid] = make_float2(xr, xi);
    }
    __syncthreads();
    // write local scan as 4 bf16 planes (split once here; gemm2 just copies)
    #pragma unroll
    for (int it = 0; it < 16; it++) {
        int lin = tid + it * 256;              // 4096 float2-pairs
        int row = lin >> 5;                    // 32 pairs per row
        int c2  = lin & 31;
        float4 v = *(const float4*)&xs[row * 64 + c2 * 2];  // (re0,im0,re1,im1)
        ushort2 rh, rl, ih, il;
        splitf(v.x, rh.x, rl.x);
        splitf(v.y, ih.x, il.x);
        splitf(v.z, rh.y, rl.y);
        splitf(v.w, ih.y, il.y);
        size_t o = (size_t)(m0 + row) * P_SZ + n0 + c2 * 2;
        *(ushort2*)&Xpl[o] = rh;
        *(ushort2*)&Xpl[MP + o] = rl;
        *(ushort2*)&Xpl[2 * MP + o] = ih;
        *(ushort2*)&Xpl[3 * MP + o] = il;
    }
}

__global__ void scanB_k(float2* __restrict__ carries,
                        const float2* __restrict__ AS) {
    int tid = blockIdx.x * blockDim.x + threadIdx.x;
    int p = tid & (P_SZ - 1);
    int b = tid / P_SZ;
    float2 A = AS[p];
    float cr = 0.f, ci = 0.f;
    for (int c = 0; c < NCH; c++) {
        int idx = (b * NCH + c) * P_SZ + p;
        float2 t = carries[idx];
        carries[idx] = make_float2(cr, ci);
        float nr = fmaf(A.x, cr, fmaf(-A.y, ci, t.x));
        float ni = fmaf(A.x, ci, fmaf(A.y, cr, t.y));
        cr = nr; ci = ni;
    }
}

// In-place carry fix-up on the X planes: x_global = x_local + Lbar^(t+1)*carry.
// hi+lo reconstruction is exact to 2^-18 (all the MFMA ever consumed).
__global__ __launch_bounds__(256) void xfix_k(unsigned short* __restrict__ Xpl,
                                              const float2* __restrict__ PpowS,
                                              const float2* __restrict__ Lbar,
                                              const float2* __restrict__ carries) {
    int t = blockIdx.x * 256 + threadIdx.x;
    int pc = t & 255;                  // p-pair index (2 columns)
    int rb = t >> 8;                   // 8-row block
    int p0 = pc * 2;
    int m0 = rb * 8;
    int g = m0 >> 7;                   // chunk
    int r = (m0 & 127) >> 3;           // stepped-power row
    float4 cv = *(const float4*)&carries[(size_t)g * P_SZ + p0];
    float4 wv = *(const float4*)&PpowS[(size_t)r * P_SZ + p0];
    float4 lb = *(const float4*)&Lbar[p0];
    float d0r = wv.x * cv.x - wv.y * cv.y;
    float d0i = wv.x * cv.y + wv.y * cv.x;
    float d1r = wv.z * cv.z - wv.w * cv.w;
    float d1i = wv.z * cv.w + wv.w * cv.z;
    #pragma unroll
    for (int q = 0; q < 8; q++) {
        size_t o = (size_t)(m0 + q) * P_SZ + p0;
        ushort2 rh = *(const ushort2*)&Xpl[o];
        ushort2 rl = *(const ushort2*)&Xpl[MP + o];
        ushort2 ih = *(const ushort2*)&Xpl[2 * MP + o];
        ushort2 il = *(const ushort2*)&Xpl[3 * MP + o];
        float xr0 = b2f(rh.x) + b2f(rl.x) + d0r;
        float xi0 = b2f(ih.x) + b2f(il.x) + d0i;
        float xr1 = b2f(rh.y) + b2f(rl.y) + d1r;
        float xi1 = b2f(ih.y) + b2f(il.y) + d1i;
        float t0r = d0r * lb.x - d0i * lb.y;
        float t0i = d0r * lb.y + d0i * lb.x;
        float t1r = d1r * lb.z - d1i * lb.w;
        float t1i = d1r * lb.w + d1i * lb.z;
        d0r = t0r; d0i = t0i; d1r = t1r; d1i = t1i;
        splitf(xr0, rh.x, rl.x);
        splitf(xi0, ih.x, il.x);
        splitf(xr1, rh.y, rl.y);
        splitf(xi1, ih.y, il.y);
        *(ushort2*)&Xpl[o] = rh;
        *(ushort2*)&Xpl[MP + o] = rl;
        *(ushort2*)&Xpl[2 * MP + o] = ih;
        *(ushort2*)&Xpl[3 * MP + o] = il;
    }
}

// GEMM2: Y = 2*(Xre*Cre - Xim*Cim). Staging is now pure int4 plane copies.
__global__ __launch_bounds__(256) void gemm2_k(const unsigned short* __restrict__ Xpl,
                                               const unsigned short* __restrict__ Cpl,
                                               float* __restrict__ Y) {
    __shared__ unsigned short sXrh[128 * 32];
    __shared__ unsigned short sXrl[128 * 32];
    __shared__ unsigned short sXih[128 * 32];
    __shared__ unsigned short sXil[128 * 32];
    __shared__ unsigned short sC[4][64 * 32];
    const int tid = threadIdx.x;
    int g, nb;
    deswizzle(blockIdx.x, g, nb);
    const int m0 = g * 128;
    const int n0 = nb * 64;
    const int lane = tid & 63, wv = tid >> 6;
    const int wm = wv & 1, wn = wv >> 1;
    const int lr = lane & 15, kg = lane >> 4;

    f32x4 acc[4][2];
    #pragma unroll
    for (int i = 0; i < 4; i++)
        #pragma unroll
        for (int j = 0; j < 2; j++) acc[i][j] = (f32x4)0.0f;

    const int srow = tid >> 2, sc8 = tid & 3;

    int4 xst[8], cst[4];
    #pragma unroll
    for (int q = 0; q < 8; q++)
        xst[q] = *(const int4*)&Xpl[(size_t)(q >> 1) * MP + (size_t)(m0 + (q & 1) * 64 + srow) * P_SZ + sc8 * 8];
    #pragma unroll
    for (int q = 0; q < 4; q++)
        cst[q] = *(const int4*)&Cpl[(size_t)q * PH + (size_t)(n0 + srow) * P_SZ + sc8 * 8];

    for (int k0 = 0; k0 < P_SZ; k0 += 32) {
        __syncthreads();
        {
            unsigned short* const sX[4] = {sXrh, sXrl, sXih, sXil};
            #pragma unroll
            for (int q = 0; q < 8; q++)
                *(int4*)&sX[q >> 1][((q & 1) * 64 + srow) * 32 + sc8 * 8] = xst[q];
        }
        #pragma unroll
        for (int q = 0; q < 4; q++)
            *(int4*)&sC[q][srow * 32 + sc8 * 8] = cst[q];
        __syncthreads();
        if (k0 + 32 < P_SZ) {
            #pragma unroll
            for (int q = 0; q < 8; q++)
                xst[q] = *(const int4*)&Xpl[(size_t)(q >> 1) * MP + (size_t)(m0 + (q & 1) * 64 + srow) * P_SZ + k0 + 32 + sc8 * 8];
            #pragma unroll
            for (int q = 0; q < 4; q++)
                cst[q] = *(const int4*)&Cpl[(size_t)q * PH + (size_t)(n0 + srow) * P_SZ + k0 + 32 + sc8 * 8];
        }

        bf16x8 xrh[4], xrl[4], xih[4], xil[4];
        #pragma unroll
        for (int mi = 0; mi < 4; mi++) {
            int off = (wm * 64 + mi * 16 + lr) * 32 + kg * 8;
            xrh[mi] = *(const bf16x8*)&sXrh[off];
            xrl[mi] = *(const bf16x8*)&sXrl[off];
            xih[mi] = *(const bf16x8*)&sXih[off];
            xil[mi] = *(const bf16x8*)&sXil[off];
        }
        bf16x8 crh[2], crl[2], cih[2], cil[2];
        #pragma unroll
        for (int nj = 0; nj < 2; nj++) {
            int off = (wn * 32 + nj * 16 + lr) * 32 + kg * 8;
            crh[nj] = *(const bf16x8*)&sC[0][off];
            crl[nj] = *(const bf16x8*)&sC[1][off];
            cih[nj] = *(const bf16x8*)&sC[2][off];
            cil[nj] = *(const bf16x8*)&sC[3][off];
        }
        #pragma unroll
        for (int mi = 0; mi < 4; mi++)
            #pragma unroll
            for (int nj = 0; nj < 2; nj++) {
                acc[mi][nj] = __builtin_amdgcn_mfma_f32_16x16x32_bf16(xrh[mi], crh[nj], acc[mi][nj], 0, 0, 0);
                acc[mi][nj] = __builtin_amdgcn_mfma_f32_16x16x32_bf16(xrh[mi], crl[nj], acc[mi][nj], 0, 0, 0);
                acc[mi][nj] = __builtin_amdgcn_mfma_f32_16x16x32_bf16(xrl[mi], crh[nj], acc[mi][nj], 0, 0, 0);
                acc[mi][nj] = __builtin_amdgcn_mfma_f32_16x16x32_bf16(xih[mi], cih[nj], acc[mi][nj], 0, 0, 0);
                acc[mi][nj] = __builtin_amdgcn_mfma_f32_16x16x32_bf16(xih[mi], cil[nj], acc[mi][nj], 0, 0, 0);
                acc[mi][nj] = __builtin_amdgcn_mfma_f32_16x16x32_bf16(xil[mi], cih[nj], acc[mi][nj], 0, 0, 0);
            }
    }
    #pragma unroll
    for (int mi = 0; mi < 4; mi++)
        #pragma unroll
        for (int nj = 0; nj < 2; nj++)
            #pragma unroll
            for (int r = 0; r < 4; r++) {
                int m = m0 + wm * 64 + mi * 16 + kg * 4 + r;
                int h = n0 + wn * 32 + nj * 16 + lr;
                Y[(size_t)m * H_SZ + h] = 2.0f * acc[mi][nj][r];
            }
}

extern "C" void kernel_launch(void* const* d_in, const int* in_sizes, int n_in,
                              void* d_out, int out_size, void* d_ws, size_t ws_size,
                              hipStream_t stream) {
    const float* lam_re   = (const float*)d_in[0];
    const float* lam_im   = (const float*)d_in[1];
    const float* Bre      = (const float*)d_in[2];
    const float* Bim      = (const float*)d_in[3];
    const float* Cre      = (const float*)d_in[4];
    const float* Cim      = (const float*)d_in[5];
    const float* log_step = (const float*)d_in[6];
    const float* U        = (const float*)d_in[7];
    float* Y = (float*)d_out;

    char* ws = (char*)d_ws;
    unsigned short* Xpl = (unsigned short*)ws;                  // 134.2 MB (4 planes)
    ws += 4 * MP * sizeof(unsigned short);
    unsigned short* Upl = (unsigned short*)ws;                  // 67.1 MB (2 planes)
    ws += 2 * MH * sizeof(unsigned short);
    unsigned short* Wpl = (unsigned short*)ws;                  // 2 MB
    ws += (size_t)4 * PH * sizeof(unsigned short);
    unsigned short* Cpl = (unsigned short*)ws;                  // 2 MB
    ws += (size_t)4 * PH * sizeof(unsigned short);
    float2* Lbar = (float2*)ws;  ws += P_SZ * sizeof(float2);
    float2* AS   = (float2*)ws;  ws += P_SZ * sizeof(float2);
    float2* scale = (float2*)ws; ws += P_SZ * sizeof(float2);
    float2* carries = (float2*)ws;                              // 1 MB
    ws += (size_t)B_SZ * NCH * P_SZ * sizeof(float2);
    float2* PpowS = (float2*)ws;                                // 64 KB

    precompute_k<<<dim3((P_SZ + 255) / 256), dim3(256), 0, stream>>>(
        lam_re, lam_im, log_step, Lbar, AS, scale);
    ppows_k<<<dim3((16 * P_SZ) / 256), dim3(256), 0, stream>>>(Lbar, PpowS);
    bbar_k<<<dim3(PH / 256), dim3(256), 0, stream>>>(Bre, Bim, scale, Wpl);
    csplit_k<<<dim3(PH / 256), dim3(256), 0, stream>>>(Cre, Cim, Cpl);
    usplit_k<<<dim3((int)(MH / 4 / 256)), dim3(256), 0, stream>>>(U, Upl);
    gemm1_k<<<dim3((M_SZ / 128) * (P_SZ / 64)), dim3(256), 0, stream>>>(Upl, Wpl, Lbar, Xpl, carries);
    scanB_k<<<dim3((B_SZ * P_SZ) / 256), dim3(256), 0, stream>>>(carries, AS);
    xfix_k<<<dim3((int)(MP / 16 / 256)), dim3(256), 0, stream>>>(Xpl, PpowS, Lbar, carries);
    gemm2_k<<<dim3((M_SZ / 128) * (H_SZ / 64)), dim3(256), 0, stream>>>(Xpl, Cpl, Y);
}

// Round 2
// 441.584 us; speedup vs baseline: 1.9441x; 1.9441x over previous
//
#include <hip/hip_runtime.h>

#define B_SZ 8
#define L_SZ 4096
#define H_SZ 512
#define P_SZ 512
#define M_SZ (B_SZ * L_SZ)      // 32768
#define NCH 32
#define CHUNK (L_SZ / NCH)      // 128
#define PH (P_SZ * H_SZ)
#define MH ((size_t)M_SZ * H_SZ)
#define MP ((size_t)M_SZ * P_SZ)

typedef __attribute__((ext_vector_type(8))) __bf16 bf16x8;
typedef __attribute__((ext_vector_type(4))) float f32x4;

// RNE fp32 -> bf16 split: x ~= hi + lo, each bf16. Error ~2^-18 relative.
__device__ __forceinline__ void splitf(float x, unsigned short& h, unsigned short& l) {
    unsigned u = __float_as_uint(x);
    unsigned hr = (u + 0x7fffu + ((u >> 16) & 1u)) >> 16;
    h = (unsigned short)hr;
    float lo = x - __uint_as_float(hr << 16);       // exact (Sterbenz)
    unsigned ul = __float_as_uint(lo);
    l = (unsigned short)((ul + 0x7fffu + ((ul >> 16) & 1u)) >> 16);
}

__device__ __forceinline__ float b2f(unsigned short s) {
    return __uint_as_float(((unsigned)s) << 16);
}

__global__ void precompute_k(const float* __restrict__ lam_re,
                             const float* __restrict__ lam_im,
                             const float* __restrict__ log_step,
                             float2* __restrict__ Lbar,
                             float2* __restrict__ AS,
                             float2* __restrict__ scale) {
    int p = blockIdx.x * blockDim.x + threadIdx.x;
    if (p >= P_SZ) return;
    float lr = lam_re[p], li = lam_im[p];
    float dt = expf(log_step[p]);
    float zr = lr * dt, zi = li * dt;
    float er = expf(zr);
    float ar = er * cosf(zi), ai = er * sinf(zi);
    Lbar[p] = make_float2(ar, ai);
    float nr = ar - 1.0f, ni = ai;
    float d2 = lr * lr + li * li;
    scale[p] = make_float2((nr * lr + ni * li) / d2, (ni * lr - nr * li) / d2);
    float xr = ar, xi = ai;
    #pragma unroll
    for (int i = 0; i < 7; i++) {      // A^128 via squarings
        float tr = xr * xr - xi * xi;
        float ti = 2.0f * xr * xi;
        xr = tr; xi = ti;
    }
    AS[p] = make_float2(xr, xi);
}

// PpowS[r][p] = Lbar[p]^(8r+1), r in [0,16)  (64 KB, stays L2-hot)
__global__ void ppows_k(const float2* __restrict__ Lbar,
                        float2* __restrict__ PpowS) {
    int idx = blockIdx.x * blockDim.x + threadIdx.x;   // r*P + p
    if (idx >= 16 * P_SZ) return;
    int p = idx & (P_SZ - 1);
    int r = idx >> 9;
    int e = 8 * r + 1;                                  // 1..121
    float2 base = Lbar[p];
    float rr = 1.0f, ri = 0.0f;
    float br = base.x, bi = base.y;
    #pragma unroll
    for (int bit = 0; bit < 7; bit++) {
        if ((e >> bit) & 1) {
            float nr = rr * br - ri * bi;
            float ni = rr * bi + ri * br;
            rr = nr; ri = ni;
        }
        float sr = br * br - bi * bi;
        float si = 2.0f * br * bi;
        br = sr; bi = si;
    }
    PpowS[idx] = make_float2(rr, ri);
}

// B_bar = scale * (Bre + i Bim), split into 4 bf16 planes [wre_h|wre_l|wim_h|wim_l]
__global__ void bbar_k(const float* __restrict__ Bre,
                       const float* __restrict__ Bim,
                       const float2* __restrict__ scale,
                       unsigned short* __restrict__ Wpl) {
    int idx = blockIdx.x * blockDim.x + threadIdx.x;
    if (idx >= PH) return;
    int p = idx / H_SZ;
    float2 s = scale[p];
    float br = Bre[idx], bi = Bim[idx];
    float wr = s.x * br - s.y * bi;
    float wi = s.x * bi + s.y * br;
    unsigned short h, l;
    splitf(wr, h, l);
    Wpl[idx] = h; Wpl[PH + idx] = l;
    splitf(wi, h, l);
    Wpl[2 * PH + idx] = h; Wpl[3 * PH + idx] = l;
}

// C planes: [cre_h|cre_l|cimn_h|cimn_l] where cimn = -Cim
__global__ void csplit_k(const float* __restrict__ Cre,
                         const float* __restrict__ Cim,
                         unsigned short* __restrict__ Cpl) {
    int idx = blockIdx.x * blockDim.x + threadIdx.x;
    if (idx >= PH) return;
    unsigned short h, l;
    splitf(Cre[idx], h, l);
    Cpl[idx] = h; Cpl[PH + idx] = l;
    splitf(-Cim[idx], h, l);
    Cpl[2 * PH + idx] = h; Cpl[3 * PH + idx] = l;
}

// U -> 2 bf16 planes [uh|ul], done ONCE (the old in-gemm1 split was 8x redundant)
__global__ __launch_bounds__(256) void usplit_k(const float* __restrict__ U,
                                                unsigned short* __restrict__ Upl) {
    size_t i4 = (size_t)blockIdx.x * 256 + threadIdx.x;
    float4 v = *(const float4*)&U[i4 * 4];
    ushort4 h, l;
    splitf(v.x, h.x, l.x);
    splitf(v.y, h.y, l.y);
    splitf(v.z, h.z, l.z);
    splitf(v.w, h.w, l.w);
    *(ushort4*)&Upl[i4 * 4] = h;
    *(ushort4*)&Upl[MH + i4 * 4] = l;
}

// swizzle: id = (m&7) + n*8 + (m>>3)*64  ->  same-m blocks share an XCD AND
// are within a 64-id dispatch window (co-resident => L2 temporal locality).
__device__ __forceinline__ void deswizzle(int bid, int& m, int& n) {
    int xcd = bid & 7;
    n = (bid >> 3) & 7;
    m = ((bid >> 6) << 3) + xcd;
}

// GEMM1: pure plane-copy staging (no in-loop splitf), fused LOCAL scan over the
// 128-row chunk (zero carry-in). Epilogue writes the local scan as 4 bf16
// planes Xpl[rh|rl|ih|il]. All LDS staging addresses are statically named --
// NO pointer arrays / pointer selects (those demote to scratch, rule #20).
__global__ __launch_bounds__(256) void gemm1_k(const unsigned short* __restrict__ Upl,
                                               const unsigned short* __restrict__ Wpl,
                                               const float2* __restrict__ Lbar,
                                               unsigned short* __restrict__ Xpl,
                                               float2* __restrict__ carries) {
    __shared__ __align__(16) char smem[65536];
    unsigned short* sUh = (unsigned short*)smem;        // 8KB
    unsigned short* sUl = sUh + 128 * 32;               // 8KB
    unsigned short* sW  = sUl + 128 * 32;               // 16KB
    const int tid = threadIdx.x;
    int g, nb;
    deswizzle(blockIdx.x, g, nb);
    const int m0 = g * 128;
    const int n0 = nb * 64;
    const int lane = tid & 63, wv = tid >> 6;
    const int wm = wv & 1, wn = wv >> 1;
    const int lr = lane & 15, kg = lane >> 4;

    f32x4 accr[4][2], acci[4][2];
    #pragma unroll
    for (int i = 0; i < 4; i++)
        #pragma unroll
        for (int j = 0; j < 2; j++) { accr[i][j] = (f32x4)0.0f; acci[i][j] = (f32x4)0.0f; }

    const int srow = tid >> 2, sc8 = tid & 3;
    const int so = srow * 32 + sc8 * 8;

    int4 uh0, uh1, ul0, ul1;
    int4 wst0, wst1, wst2, wst3;
    uh0 = *(const int4*)&Upl[(size_t)(m0 + srow) * H_SZ + sc8 * 8];
    uh1 = *(const int4*)&Upl[(size_t)(m0 + 64 + srow) * H_SZ + sc8 * 8];
    ul0 = *(const int4*)&Upl[MH + (size_t)(m0 + srow) * H_SZ + sc8 * 8];
    ul1 = *(const int4*)&Upl[MH + (size_t)(m0 + 64 + srow) * H_SZ + sc8 * 8];
    wst0 = *(const int4*)&Wpl[(size_t)(n0 + srow) * H_SZ + sc8 * 8];
    wst1 = *(const int4*)&Wpl[PH + (size_t)(n0 + srow) * H_SZ + sc8 * 8];
    wst2 = *(const int4*)&Wpl[2 * PH + (size_t)(n0 + srow) * H_SZ + sc8 * 8];
    wst3 = *(const int4*)&Wpl[3 * PH + (size_t)(n0 + srow) * H_SZ + sc8 * 8];

    for (int k0 = 0; k0 < H_SZ; k0 += 32) {
        __syncthreads();
        *(int4*)&sUh[so] = uh0;
        *(int4*)&sUh[64 * 32 + so] = uh1;
        *(int4*)&sUl[so] = ul0;
        *(int4*)&sUl[64 * 32 + so] = ul1;
        *(int4*)&sW[0 * 2048 + so] = wst0;
        *(int4*)&sW[1 * 2048 + so] = wst1;
        *(int4*)&sW[2 * 2048 + so] = wst2;
        *(int4*)&sW[3 * 2048 + so] = wst3;
        __syncthreads();
        if (k0 + 32 < H_SZ) {
            int k1 = k0 + 32;
            uh0 = *(const int4*)&Upl[(size_t)(m0 + srow) * H_SZ + k1 + sc8 * 8];
            uh1 = *(const int4*)&Upl[(size_t)(m0 + 64 + srow) * H_SZ + k1 + sc8 * 8];
            ul0 = *(const int4*)&Upl[MH + (size_t)(m0 + srow) * H_SZ + k1 + sc8 * 8];
            ul1 = *(const int4*)&Upl[MH + (size_t)(m0 + 64 + srow) * H_SZ + k1 + sc8 * 8];
            wst0 = *(const int4*)&Wpl[(size_t)(n0 + srow) * H_SZ + k1 + sc8 * 8];
            wst1 = *(const int4*)&Wpl[PH + (size_t)(n0 + srow) * H_SZ + k1 + sc8 * 8];
            wst2 = *(const int4*)&Wpl[2 * PH + (size_t)(n0 + srow) * H_SZ + k1 + sc8 * 8];
            wst3 = *(const int4*)&Wpl[3 * PH + (size_t)(n0 + srow) * H_SZ + k1 + sc8 * 8];
        }

        bf16x8 uh[4], ul[4];
        #pragma unroll
        for (int mi = 0; mi < 4; mi++) {
            int off = (wm * 64 + mi * 16 + lr) * 32 + kg * 8;
            uh[mi] = *(const bf16x8*)&sUh[off];
            ul[mi] = *(const bf16x8*)&sUl[off];
        }
        bf16x8 wrh[2], wrl[2], wih[2], wil[2];
        #pragma unroll
        for (int nj = 0; nj < 2; nj++) {
            int off = (wn * 32 + nj * 16 + lr) * 32 + kg * 8;
            wrh[nj] = *(const bf16x8*)&sW[0 * 2048 + off];
            wrl[nj] = *(const bf16x8*)&sW[1 * 2048 + off];
            wih[nj] = *(const bf16x8*)&sW[2 * 2048 + off];
            wil[nj] = *(const bf16x8*)&sW[3 * 2048 + off];
        }
        #pragma unroll
        for (int mi = 0; mi < 4; mi++)
            #pragma unroll
            for (int nj = 0; nj < 2; nj++) {
                accr[mi][nj] = __builtin_amdgcn_mfma_f32_16x16x32_bf16(uh[mi], wrh[nj], accr[mi][nj], 0, 0, 0);
                accr[mi][nj] = __builtin_amdgcn_mfma_f32_16x16x32_bf16(uh[mi], wrl[nj], accr[mi][nj], 0, 0, 0);
                accr[mi][nj] = __builtin_amdgcn_mfma_f32_16x16x32_bf16(ul[mi], wrh[nj], accr[mi][nj], 0, 0, 0);
                acci[mi][nj] = __builtin_amdgcn_mfma_f32_16x16x32_bf16(uh[mi], wih[nj], acci[mi][nj], 0, 0, 0);
                acci[mi][nj] = __builtin_amdgcn_mfma_f32_16x16x32_bf16(uh[mi], wil[nj], acci[mi][nj], 0, 0, 0);
                acci[mi][nj] = __builtin_amdgcn_mfma_f32_16x16x32_bf16(ul[mi], wih[nj], acci[mi][nj], 0, 0, 0);
            }
    }

    // ---- epilogue: local chunk scan in LDS (reuses staging LDS) ----
    __syncthreads();
    float2* xs = (float2*)smem;                // [128 t][64 p] = 64KB
    #pragma unroll
    for (int mi = 0; mi < 4; mi++)
        #pragma unroll
        for (int nj = 0; nj < 2; nj++)
            #pragma unroll
            for (int r = 0; r < 4; r++) {
                int t = wm * 64 + mi * 16 + kg * 4 + r;
                int p = wn * 32 + nj * 16 + lr;
                xs[t * 64 + p] = make_float2(accr[mi][nj][r], acci[mi][nj][r]);
            }
    __syncthreads();
    if (tid < 64) {
        float2 A = Lbar[n0 + tid];
        float xr = 0.f, xi = 0.f;
        for (int t = 0; t < CHUNK; t++) {
            float2 v = xs[t * 64 + tid];
            float nr = fmaf(A.x, xr, fmaf(-A.y, xi, v.x));
            float ni = fmaf(A.x, xi, fmaf(A.y, xr, v.y));
            xr = nr; xi = ni;
            xs[t * 64 + tid] = make_float2(xr, xi);
        }
        carries[(size_t)g * P_SZ + n0 + tid] = make_float2(xr, xi);
    }
    __syncthreads();
    // write local scan as 4 bf16 planes (split once here; gemm2 just copies)
    #pragma unroll
    for (int it = 0; it < 16; it++) {
        int lin = tid + it * 256;              // 4096 float2-pairs
        int row = lin >> 5;                    // 32 pairs per row
        int c2  = lin & 31;
        float4 v = *(const float4*)&xs[row * 64 + c2 * 2];  // (re0,im0,re1,im1)
        ushort2 rh, rl, ih, il;
        splitf(v.x, rh.x, rl.x);
        splitf(v.y, ih.x, il.x);
        splitf(v.z, rh.y, rl.y);
        splitf(v.w, ih.y, il.y);
        size_t o = (size_t)(m0 + row) * P_SZ + n0 + c2 * 2;
        *(ushort2*)&Xpl[o] = rh;
        *(ushort2*)&Xpl[MP + o] = rl;
        *(ushort2*)&Xpl[2 * MP + o] = ih;
        *(ushort2*)&Xpl[3 * MP + o] = il;
    }
}

__global__ void scanB_k(float2* __restrict__ carries,
                        const float2* __restrict__ AS) {
    int tid = blockIdx.x * blockDim.x + threadIdx.x;
    int p = tid & (P_SZ - 1);
    int b = tid / P_SZ;
    float2 A = AS[p];
    float cr = 0.f, ci = 0.f;
    for (int c = 0; c < NCH; c++) {
        int idx = (b * NCH + c) * P_SZ + p;
        float2 t = carries[idx];
        carries[idx] = make_float2(cr, ci);
        float nr = fmaf(A.x, cr, fmaf(-A.y, ci, t.x));
        float ni = fmaf(A.x, ci, fmaf(A.y, cr, t.y));
        cr = nr; ci = ni;
    }
}

// In-place carry fix-up on the X planes: x_global = x_local + Lbar^(t+1)*carry.
// hi+lo reconstruction is exact to 2^-18 (all the MFMA ever consumed).
__global__ __launch_bounds__(256) void xfix_k(unsigned short* __restrict__ Xpl,
                                              const float2* __restrict__ PpowS,
                                              const float2* __restrict__ Lbar,
                                              const float2* __restrict__ carries) {
    int t = blockIdx.x * 256 + threadIdx.x;
    int pc = t & 255;                  // p-pair index (2 columns)
    int rb = t >> 8;                   // 8-row block
    int p0 = pc * 2;
    int m0 = rb * 8;
    int g = m0 >> 7;                   // chunk
    int r = (m0 & 127) >> 3;           // stepped-power row
    float4 cv = *(const float4*)&carries[(size_t)g * P_SZ + p0];
    float4 wv = *(const float4*)&PpowS[(size_t)r * P_SZ + p0];
    float4 lb = *(const float4*)&Lbar[p0];
    float d0r = wv.x * cv.x - wv.y * cv.y;
    float d0i = wv.x * cv.y + wv.y * cv.x;
    float d1r = wv.z * cv.z - wv.w * cv.w;
    float d1i = wv.z * cv.w + wv.w * cv.z;
    #pragma unroll
    for (int q = 0; q < 8; q++) {
        size_t o = (size_t)(m0 + q) * P_SZ + p0;
        ushort2 rh = *(const ushort2*)&Xpl[o];
        ushort2 rl = *(const ushort2*)&Xpl[MP + o];
        ushort2 ih = *(const ushort2*)&Xpl[2 * MP + o];
        ushort2 il = *(const ushort2*)&Xpl[3 * MP + o];
        float xr0 = b2f(rh.x) + b2f(rl.x) + d0r;
        float xi0 = b2f(ih.x) + b2f(il.x) + d0i;
        float xr1 = b2f(rh.y) + b2f(rl.y) + d1r;
        float xi1 = b2f(ih.y) + b2f(il.y) + d1i;
        float t0r = d0r * lb.x - d0i * lb.y;
        float t0i = d0r * lb.y + d0i * lb.x;
        float t1r = d1r * lb.z - d1i * lb.w;
        float t1i = d1r * lb.w + d1i * lb.z;
        d0r = t0r; d0i = t0i; d1r = t1r; d1i = t1i;
        splitf(xr0, rh.x, rl.x);
        splitf(xi0, ih.x, il.x);
        splitf(xr1, rh.y, rl.y);
        splitf(xi1, ih.y, il.y);
        *(ushort2*)&Xpl[o] = rh;
        *(ushort2*)&Xpl[MP + o] = rl;
        *(ushort2*)&Xpl[2 * MP + o] = ih;
        *(ushort2*)&Xpl[3 * MP + o] = il;
    }
}

// GEMM2: Y = 2*(Xre*Cre - Xim*Cim). Staging is pure int4 plane copies with
// statically named destinations (no pointer arrays -> no scratch).
__global__ __launch_bounds__(256) void gemm2_k(const unsigned short* __restrict__ Xpl,
                                               const unsigned short* __restrict__ Cpl,
                                               float* __restrict__ Y) {
    __shared__ unsigned short sXrh[128 * 32];
    __shared__ unsigned short sXrl[128 * 32];
    __shared__ unsigned short sXih[128 * 32];
    __shared__ unsigned short sXil[128 * 32];
    __shared__ unsigned short sC[4][64 * 32];
    const int tid = threadIdx.x;
    int g, nb;
    deswizzle(blockIdx.x, g, nb);
    const int m0 = g * 128;
    const int n0 = nb * 64;
    const int lane = tid & 63, wv = tid >> 6;
    const int wm = wv & 1, wn = wv >> 1;
    const int lr = lane & 15, kg = lane >> 4;

    f32x4 acc[4][2];
    #pragma unroll
    for (int i = 0; i < 4; i++)
        #pragma unroll
        for (int j = 0; j < 2; j++) acc[i][j] = (f32x4)0.0f;

    const int srow = tid >> 2, sc8 = tid & 3;
    const int so = srow * 32 + sc8 * 8;

    int4 xrh0, xrh1, xrl0, xrl1, xih0, xih1, xil0, xil1;
    int4 cst0, cst1, cst2, cst3;
    xrh0 = *(const int4*)&Xpl[(size_t)(m0 + srow) * P_SZ + sc8 * 8];
    xrh1 = *(const int4*)&Xpl[(size_t)(m0 + 64 + srow) * P_SZ + sc8 * 8];
    xrl0 = *(const int4*)&Xpl[MP + (size_t)(m0 + srow) * P_SZ + sc8 * 8];
    xrl1 = *(const int4*)&Xpl[MP + (size_t)(m0 + 64 + srow) * P_SZ + sc8 * 8];
    xih0 = *(const int4*)&Xpl[2 * MP + (size_t)(m0 + srow) * P_SZ + sc8 * 8];
    xih1 = *(const int4*)&Xpl[2 * MP + (size_t)(m0 + 64 + srow) * P_SZ + sc8 * 8];
    xil0 = *(const int4*)&Xpl[3 * MP + (size_t)(m0 + srow) * P_SZ + sc8 * 8];
    xil1 = *(const int4*)&Xpl[3 * MP + (size_t)(m0 + 64 + srow) * P_SZ + sc8 * 8];
    cst0 = *(const int4*)&Cpl[(size_t)(n0 + srow) * P_SZ + sc8 * 8];
    cst1 = *(const int4*)&Cpl[PH + (size_t)(n0 + srow) * P_SZ + sc8 * 8];
    cst2 = *(const int4*)&Cpl[2 * PH + (size_t)(n0 + srow) * P_SZ + sc8 * 8];
    cst3 = *(const int4*)&Cpl[3 * PH + (size_t)(n0 + srow) * P_SZ + sc8 * 8];

    for (int k0 = 0; k0 < P_SZ; k0 += 32) {
        __syncthreads();
        *(int4*)&sXrh[so] = xrh0;
        *(int4*)&sXrh[64 * 32 + so] = xrh1;
        *(int4*)&sXrl[so] = xrl0;
        *(int4*)&sXrl[64 * 32 + so] = xrl1;
        *(int4*)&sXih[so] = xih0;
        *(int4*)&sXih[64 * 32 + so] = xih1;
        *(int4*)&sXil[so] = xil0;
        *(int4*)&sXil[64 * 32 + so] = xil1;
        *(int4*)&sC[0][so] = cst0;
        *(int4*)&sC[1][so] = cst1;
        *(int4*)&sC[2][so] = cst2;
        *(int4*)&sC[3][so] = cst3;
        __syncthreads();
        if (k0 + 32 < P_SZ) {
            int k1 = k0 + 32;
            xrh0 = *(const int4*)&Xpl[(size_t)(m0 + srow) * P_SZ + k1 + sc8 * 8];
            xrh1 = *(const int4*)&Xpl[(size_t)(m0 + 64 + srow) * P_SZ + k1 + sc8 * 8];
            xrl0 = *(const int4*)&Xpl[MP + (size_t)(m0 + srow) * P_SZ + k1 + sc8 * 8];
            xrl1 = *(const int4*)&Xpl[MP + (size_t)(m0 + 64 + srow) * P_SZ + k1 + sc8 * 8];
            xih0 = *(const int4*)&Xpl[2 * MP + (size_t)(m0 + srow) * P_SZ + k1 + sc8 * 8];
            xih1 = *(const int4*)&Xpl[2 * MP + (size_t)(m0 + 64 + srow) * P_SZ + k1 + sc8 * 8];
            xil0 = *(const int4*)&Xpl[3 * MP + (size_t)(m0 + srow) * P_SZ + k1 + sc8 * 8];
            xil1 = *(const int4*)&Xpl[3 * MP + (size_t)(m0 + 64 + srow) * P_SZ + k1 + sc8 * 8];
            cst0 = *(const int4*)&Cpl[(size_t)(n0 + srow) * P_SZ + k1 + sc8 * 8];
            cst1 = *(const int4*)&Cpl[PH + (size_t)(n0 + srow) * P_SZ + k1 + sc8 * 8];
            cst2 = *(const int4*)&Cpl[2 * PH + (size_t)(n0 + srow) * P_SZ + k1 + sc8 * 8];
            cst3 = *(const int4*)&Cpl[3 * PH + (size_t)(n0 + srow) * P_SZ + k1 + sc8 * 8];
        }

        bf16x8 xrh[4], xrl[4], xih[4], xil[4];
        #pragma unroll
        for (int mi = 0; mi < 4; mi++) {
            int off = (wm * 64 + mi * 16 + lr) * 32 + kg * 8;
            xrh[mi] = *(const bf16x8*)&sXrh[off];
            xrl[mi] = *(const bf16x8*)&sXrl[off];
            xih[mi] = *(const bf16x8*)&sXih[off];
            xil[mi] = *(const bf16x8*)&sXil[off];
        }
        bf16x8 crh[2], crl[2], cih[2], cil[2];
        #pragma unroll
        for (int nj = 0; nj < 2; nj++) {
            int off = (wn * 32 + nj * 16 + lr) * 32 + kg * 8;
            crh[nj] = *(const bf16x8*)&sC[0][off];
            crl[nj] = *(const bf16x8*)&sC[1][off];
            cih[nj] = *(const bf16x8*)&sC[2][off];
            cil[nj] = *(const bf16x8*)&sC[3][off];
        }
        #pragma unroll
        for (int mi = 0; mi < 4; mi++)
            #pragma unroll
            for (int nj = 0; nj < 2; nj++) {
                acc[mi][nj] = __builtin_amdgcn_mfma_f32_16x16x32_bf16(xrh[mi], crh[nj], acc[mi][nj], 0, 0, 0);
                acc[mi][nj] = __builtin_amdgcn_mfma_f32_16x16x32_bf16(xrh[mi], crl[nj], acc[mi][nj], 0, 0, 0);
                acc[mi][nj] = __builtin_amdgcn_mfma_f32_16x16x32_bf16(xrl[mi], crh[nj], acc[mi][nj], 0, 0, 0);
                acc[mi][nj] = __builtin_amdgcn_mfma_f32_16x16x32_bf16(xih[mi], cih[nj], acc[mi][nj], 0, 0, 0);
                acc[mi][nj] = __builtin_amdgcn_mfma_f32_16x16x32_bf16(xih[mi], cil[nj], acc[mi][nj], 0, 0, 0);
                acc[mi][nj] = __builtin_amdgcn_mfma_f32_16x16x32_bf16(xil[mi], cih[nj], acc[mi][nj], 0, 0, 0);
            }
    }
    #pragma unroll
    for (int mi = 0; mi < 4; mi++)
        #pragma unroll
        for (int nj = 0; nj < 2; nj++)
            #pragma unroll
            for (int r = 0; r < 4; r++) {
                int m = m0 + wm * 64 + mi * 16 + kg * 4 + r;
                int h = n0 + wn * 32 + nj * 16 + lr;
                Y[(size_t)m * H_SZ + h] = 2.0f * acc[mi][nj][r];
            }
}

extern "C" void kernel_launch(void* const* d_in, const int* in_sizes, int n_in,
                              void* d_out, int out_size, void* d_ws, size_t ws_size,
                              hipStream_t stream) {
    const float* lam_re   = (const float*)d_in[0];
    const float* lam_im   = (const float*)d_in[1];
    const float* Bre      = (const float*)d_in[2];
    const float* Bim      = (const float*)d_in[3];
    const float* Cre      = (const float*)d_in[4];
    const float* Cim      = (const float*)d_in[5];
    const float* log_step = (const float*)d_in[6];
    const float* U        = (const float*)d_in[7];
    float* Y = (float*)d_out;

    char* ws = (char*)d_ws;
    unsigned short* Xpl = (unsigned short*)ws;                  // 134.2 MB (4 planes)
    ws += 4 * MP * sizeof(unsigned short);
    unsigned short* Upl = (unsigned short*)ws;                  // 67.1 MB (2 planes)
    ws += 2 * MH * sizeof(unsigned short);
    unsigned short* Wpl = (unsigned short*)ws;                  // 2 MB
    ws += (size_t)4 * PH * sizeof(unsigned short);
    unsigned short* Cpl = (unsigned short*)ws;                  // 2 MB
    ws += (size_t)4 * PH * sizeof(unsigned short);
    float2* Lbar = (float2*)ws;  ws += P_SZ * sizeof(float2);
    float2* AS   = (float2*)ws;  ws += P_SZ * sizeof(float2);
    float2* scale = (float2*)ws; ws += P_SZ * sizeof(float2);
    float2* carries = (float2*)ws;                              // 1 MB
    ws += (size_t)B_SZ * NCH * P_SZ * sizeof(float2);
    float2* PpowS = (float2*)ws;                                // 64 KB

    precompute_k<<<dim3((P_SZ + 255) / 256), dim3(256), 0, stream>>>(
        lam_re, lam_im, log_step, Lbar, AS, scale);
    ppows_k<<<dim3((16 * P_SZ) / 256), dim3(256), 0, stream>>>(Lbar, PpowS);
    bbar_k<<<dim3(PH / 256), dim3(256), 0, stream>>>(Bre, Bim, scale, Wpl);
    csplit_k<<<dim3(PH / 256), dim3(256), 0, stream>>>(Cre, Cim, Cpl);
    usplit_k<<<dim3((int)(MH / 4 / 256)), dim3(256), 0, stream>>>(U, Upl);
    gemm1_k<<<dim3((M_SZ / 128) * (P_SZ / 64)), dim3(256), 0, stream>>>(Upl, Wpl, Lbar, Xpl, carries);
    scanB_k<<<dim3((B_SZ * P_SZ) / 256), dim3(256), 0, stream>>>(carries, AS);
    xfix_k<<<dim3((int)(MP / 16 / 256)), dim3(256), 0, stream>>>(Xpl, PpowS, Lbar, carries);
    gemm2_k<<<dim3((M_SZ / 128) * (H_SZ / 64)), dim3(256), 0, stream>>>(Xpl, Cpl, Y);
}

// Round 3
// 406.733 us; speedup vs baseline: 2.1107x; 1.0857x over previous
//
#include <hip/hip_runtime.h>

#define B_SZ 8
#define L_SZ 4096
#define H_SZ 512
#define P_SZ 512
#define M_SZ (B_SZ * L_SZ)      // 32768
#define NCH 32
#define CHUNK (L_SZ / NCH)      // 128
#define PH (P_SZ * H_SZ)
#define MH ((size_t)M_SZ * H_SZ)        // U plane elems
#define MK2 ((size_t)M_SZ * 1024)       // Xc plane elems (k' = 2*P)
#define KW ((size_t)1024 * 512)         // Wc / Cc plane elems
#define LDSP 40                          // padded LDS row stride in shorts (80B)

typedef __attribute__((ext_vector_type(8))) __bf16 bf16x8;
typedef __attribute__((ext_vector_type(4))) float f32x4;

// RNE fp32 -> bf16 split: x ~= hi + lo, each bf16. Error ~2^-18 relative.
__device__ __forceinline__ void splitf(float x, unsigned short& h, unsigned short& l) {
    unsigned u = __float_as_uint(x);
    unsigned hr = (u + 0x7fffu + ((u >> 16) & 1u)) >> 16;
    h = (unsigned short)hr;
    float lo = x - __uint_as_float(hr << 16);       // exact (Sterbenz)
    unsigned ul = __float_as_uint(lo);
    l = (unsigned short)((ul + 0x7fffu + ((ul >> 16) & 1u)) >> 16);
}

__device__ __forceinline__ float b2f(unsigned short s) {
    return __uint_as_float(((unsigned)s) << 16);
}

__global__ void precompute_k(const float* __restrict__ lam_re,
                             const float* __restrict__ lam_im,
                             const float* __restrict__ log_step,
                             float2* __restrict__ Lbar,
                             float2* __restrict__ AS,
                             float2* __restrict__ scale) {
    int p = blockIdx.x * blockDim.x + threadIdx.x;
    if (p >= P_SZ) return;
    float lr = lam_re[p], li = lam_im[p];
    float dt = expf(log_step[p]);
    float zr = lr * dt, zi = li * dt;
    float er = expf(zr);
    float ar = er * cosf(zi), ai = er * sinf(zi);
    Lbar[p] = make_float2(ar, ai);
    float nr = ar - 1.0f, ni = ai;
    float d2 = lr * lr + li * li;
    scale[p] = make_float2((nr * lr + ni * li) / d2, (ni * lr - nr * li) / d2);
    float xr = ar, xi = ai;
    #pragma unroll
    for (int i = 0; i < 7; i++) {      // A^128 via squarings
        float tr = xr * xr - xi * xi;
        float ti = 2.0f * xr * xi;
        xr = tr; xi = ti;
    }
    AS[p] = make_float2(xr, xi);
}

// PpowS[r][p] = Lbar[p]^(8r+1), r in [0,16)  (64 KB, stays L2-hot)
__global__ void ppows_k(const float2* __restrict__ Lbar,
                        float2* __restrict__ PpowS) {
    int idx = blockIdx.x * blockDim.x + threadIdx.x;   // r*P + p
    if (idx >= 16 * P_SZ) return;
    int p = idx & (P_SZ - 1);
    int r = idx >> 9;
    int e = 8 * r + 1;                                  // 1..121
    float2 base = Lbar[p];
    float rr = 1.0f, ri = 0.0f;
    float br = base.x, bi = base.y;
    #pragma unroll
    for (int bit = 0; bit < 7; bit++) {
        if ((e >> bit) & 1) {
            float nr = rr * br - ri * bi;
            float ni = rr * bi + ri * br;
            rr = nr; ri = ni;
        }
        float sr = br * br - bi * bi;
        float si = 2.0f * br * bi;
        br = sr; bi = si;
    }
    PpowS[idx] = make_float2(rr, ri);
}

// B_bar = scale*(Bre + i Bim). Wc rows n'=2p -> w_re row, n'=2p+1 -> w_im row,
// 2 planes [hi | lo], each [1024][512].
__global__ void bbar_k(const float* __restrict__ Bre,
                       const float* __restrict__ Bim,
                       const float2* __restrict__ scale,
                       unsigned short* __restrict__ Wc) {
    int idx = blockIdx.x * blockDim.x + threadIdx.x;
    if (idx >= PH) return;
    int p = idx / H_SZ;
    int h = idx - p * H_SZ;
    float2 s = scale[p];
    float br = Bre[idx], bi = Bim[idx];
    float wr = s.x * br - s.y * bi;
    float wi = s.x * bi + s.y * br;
    unsigned short hh, ll;
    splitf(wr, hh, ll);
    Wc[(size_t)(2 * p) * H_SZ + h] = hh;
    Wc[KW + (size_t)(2 * p) * H_SZ + h] = ll;
    splitf(wi, hh, ll);
    Wc[(size_t)(2 * p + 1) * H_SZ + h] = hh;
    Wc[KW + (size_t)(2 * p + 1) * H_SZ + h] = ll;
}

// Cc planes [hi | lo], each [512][1024]: k'=2p -> split(Cre), k'=2p+1 -> split(-Cim)
__global__ void csplit_k(const float* __restrict__ Cre,
                         const float* __restrict__ Cim,
                         unsigned short* __restrict__ Cc) {
    int idx = blockIdx.x * blockDim.x + threadIdx.x;   // h*P + p
    if (idx >= PH) return;
    int hrow = idx / P_SZ;
    int p = idx - hrow * P_SZ;
    unsigned short ah, al, bh, bl;
    splitf(Cre[idx], ah, al);
    splitf(-Cim[idx], bh, bl);
    ushort2 hi; hi.x = ah; hi.y = bh;
    ushort2 lo; lo.x = al; lo.y = bl;
    *(ushort2*)&Cc[(size_t)hrow * 1024 + 2 * p] = hi;
    *(ushort2*)&Cc[KW + (size_t)hrow * 1024 + 2 * p] = lo;
}

// U -> 2 bf16 planes [uh|ul], done ONCE
__global__ __launch_bounds__(256) void usplit_k(const float* __restrict__ U,
                                                unsigned short* __restrict__ Upl) {
    size_t i4 = (size_t)blockIdx.x * 256 + threadIdx.x;
    float4 v = *(const float4*)&U[i4 * 4];
    ushort4 h, l;
    splitf(v.x, h.x, l.x);
    splitf(v.y, h.y, l.y);
    splitf(v.z, h.z, l.z);
    splitf(v.w, h.w, l.w);
    *(ushort4*)&Upl[i4 * 4] = h;
    *(ushort4*)&Upl[MH + i4 * 4] = l;
}

// same-m blocks share an XCD and a dispatch window (L2 temporal locality)
__device__ __forceinline__ void deswizzle8(int bid, int& m, int& n) {
    int xcd = bid & 7;
    n = (bid >> 3) & 7;
    m = ((bid >> 6) << 3) + xcd;
}
__device__ __forceinline__ void deswizzle4(int bid, int& m, int& n) {
    int xcd = bid & 7;
    n = (bid >> 3) & 3;
    m = ((bid >> 5) << 3) + xcd;
}

// GEMM1: Bu[m][n'=1024] = U[m][k] * Wc[n'][k], 2-plane split (hh+hl+lh).
// Block 128x128(n'), 4 waves of 64x64. Fused local chunk scan + plane write.
__global__ __launch_bounds__(256, 2) void gemm1_k(const unsigned short* __restrict__ Upl,
                                                  const unsigned short* __restrict__ Wc,
                                                  const float2* __restrict__ Lbar,
                                                  unsigned short* __restrict__ Xc,
                                                  float2* __restrict__ carries) {
    __shared__ __align__(16) char smem[65536];
    unsigned short* sAh = (unsigned short*)smem;        // [128][LDSP]
    unsigned short* sAl = sAh + 128 * LDSP;
    unsigned short* sBh = sAl + 128 * LDSP;
    unsigned short* sBl = sBh + 128 * LDSP;             // 40960 B
    const int tid = threadIdx.x;
    int g, nb;
    deswizzle8(blockIdx.x, g, nb);
    const int m0 = g * 128;
    const int n0 = nb * 128;                            // n' base
    const int lane = tid & 63, wv = tid >> 6;
    const int wm = wv & 1, wn = wv >> 1;
    const int lr = lane & 15, kg = lane >> 4;

    f32x4 acc[4][4];
    #pragma unroll
    for (int i = 0; i < 4; i++)
        #pragma unroll
        for (int j = 0; j < 4; j++) acc[i][j] = (f32x4)0.0f;

    const int srow = tid >> 2, sc8 = tid & 3;
    const int so0 = srow * LDSP + sc8 * 8;
    const int so1 = (srow + 64) * LDSP + sc8 * 8;

    const unsigned short* gAh = Upl + (size_t)(m0 + srow) * H_SZ + sc8 * 8;
    const unsigned short* gAl = gAh + MH;
    const unsigned short* gBh = Wc + (size_t)(n0 + srow) * H_SZ + sc8 * 8;
    const unsigned short* gBl = gBh + KW;
    const size_t rs = (size_t)64 * H_SZ;

    int4 ah0 = *(const int4*)gAh, ah1 = *(const int4*)(gAh + rs);
    int4 al0 = *(const int4*)gAl, al1 = *(const int4*)(gAl + rs);
    int4 bh0 = *(const int4*)gBh, bh1 = *(const int4*)(gBh + rs);
    int4 bl0 = *(const int4*)gBl, bl1 = *(const int4*)(gBl + rs);

    for (int k0 = 0; k0 < H_SZ; k0 += 32) {
        __syncthreads();
        *(int4*)&sAh[so0] = ah0; *(int4*)&sAh[so1] = ah1;
        *(int4*)&sAl[so0] = al0; *(int4*)&sAl[so1] = al1;
        *(int4*)&sBh[so0] = bh0; *(int4*)&sBh[so1] = bh1;
        *(int4*)&sBl[so0] = bl0; *(int4*)&sBl[so1] = bl1;
        __syncthreads();
        if (k0 + 32 < H_SZ) {
            gAh += 32; gAl += 32; gBh += 32; gBl += 32;
            ah0 = *(const int4*)gAh; ah1 = *(const int4*)(gAh + rs);
            al0 = *(const int4*)gAl; al1 = *(const int4*)(gAl + rs);
            bh0 = *(const int4*)gBh; bh1 = *(const int4*)(gBh + rs);
            bl0 = *(const int4*)gBl; bl1 = *(const int4*)(gBl + rs);
        }

        bf16x8 fah[4], fal[4], fbh[4], fbl[4];
        #pragma unroll
        for (int mi = 0; mi < 4; mi++) {
            int off = (wm * 64 + mi * 16 + lr) * LDSP + kg * 8;
            fah[mi] = *(const bf16x8*)&sAh[off];
            fal[mi] = *(const bf16x8*)&sAl[off];
        }
        #pragma unroll
        for (int nj = 0; nj < 4; nj++) {
            int off = (wn * 64 + nj * 16 + lr) * LDSP + kg * 8;
            fbh[nj] = *(const bf16x8*)&sBh[off];
            fbl[nj] = *(const bf16x8*)&sBl[off];
        }
        #pragma unroll
        for (int mi = 0; mi < 4; mi++)
            #pragma unroll
            for (int nj = 0; nj < 4; nj++) {
                acc[mi][nj] = __builtin_amdgcn_mfma_f32_16x16x32_bf16(fah[mi], fbh[nj], acc[mi][nj], 0, 0, 0);
                acc[mi][nj] = __builtin_amdgcn_mfma_f32_16x16x32_bf16(fah[mi], fbl[nj], acc[mi][nj], 0, 0, 0);
                acc[mi][nj] = __builtin_amdgcn_mfma_f32_16x16x32_bf16(fal[mi], fbh[nj], acc[mi][nj], 0, 0, 0);
            }
    }

    // ---- epilogue: local chunk scan in LDS (reuses staging LDS) ----
    __syncthreads();
    float* xsf = (float*)smem;                 // [128 t][128 n'] = 64KB
    #pragma unroll
    for (int mi = 0; mi < 4; mi++)
        #pragma unroll
        for (int nj = 0; nj < 4; nj++)
            #pragma unroll
            for (int r = 0; r < 4; r++) {
                int t = wm * 64 + mi * 16 + kg * 4 + r;
                int np = wn * 64 + nj * 16 + lr;
                xsf[t * 128 + np] = acc[mi][nj][r];
            }
    __syncthreads();
    if (tid < 64) {
        float2* xs2 = (float2*)smem;           // [128 t][64 p]
        float2 A = Lbar[nb * 64 + tid];
        float xr = 0.f, xi = 0.f;
        for (int t = 0; t < CHUNK; t++) {
            float2 v = xs2[t * 64 + tid];
            float nr = fmaf(A.x, xr, fmaf(-A.y, xi, v.x));
            float ni = fmaf(A.x, xi, fmaf(A.y, xr, v.y));
            xr = nr; xi = ni;
            xs2[t * 64 + tid] = make_float2(xr, xi);
        }
        carries[(size_t)g * P_SZ + nb * 64 + tid] = make_float2(xr, xi);
    }
    __syncthreads();
    const float4* xs4 = (const float4*)smem;   // [128][32] (re,im,re,im)
    #pragma unroll
    for (int it = 0; it < 16; it++) {
        int lin = tid + it * 256;              // 4096
        int row = lin >> 5;
        int c4  = lin & 31;
        float4 v = xs4[lin];
        ushort4 h4, l4;
        splitf(v.x, h4.x, l4.x);
        splitf(v.y, h4.y, l4.y);
        splitf(v.z, h4.z, l4.z);
        splitf(v.w, h4.w, l4.w);
        size_t o = (size_t)(m0 + row) * 1024 + n0 + c4 * 4;
        *(ushort4*)&Xc[o] = h4;
        *(ushort4*)&Xc[MK2 + o] = l4;
    }
}

__global__ void scanB_k(float2* __restrict__ carries,
                        const float2* __restrict__ AS) {
    int tid = blockIdx.x * blockDim.x + threadIdx.x;
    int p = tid & (P_SZ - 1);
    int b = tid / P_SZ;
    float2 A = AS[p];
    float cr = 0.f, ci = 0.f;
    for (int c = 0; c < NCH; c++) {
        int idx = (b * NCH + c) * P_SZ + p;
        float2 t = carries[idx];
        carries[idx] = make_float2(cr, ci);
        float nr = fmaf(A.x, cr, fmaf(-A.y, ci, t.x));
        float ni = fmaf(A.x, ci, fmaf(A.y, cr, t.y));
        cr = nr; ci = ni;
    }
}

// In-place carry fix-up on the interleaved X planes:
// x_global = x_local + Lbar^(t+1)*carry  (hi+lo reconstruct is exact to 2^-18)
__global__ __launch_bounds__(256) void xfix_k(unsigned short* __restrict__ Xc,
                                              const float2* __restrict__ PpowS,
                                              const float2* __restrict__ Lbar,
                                              const float2* __restrict__ carries) {
    int t = blockIdx.x * 256 + threadIdx.x;
    int pc = t & 255;                  // complex pair p0=2pc, p0+1 -> k' = 4pc..4pc+3
    int rb = t >> 8;                   // 8-row block
    int p0 = pc * 2;
    int m0 = rb * 8;
    int g = m0 >> 7;                   // chunk
    int r = (m0 & 127) >> 3;           // stepped-power row
    float4 cv = *(const float4*)&carries[(size_t)g * P_SZ + p0];
    float4 wv = *(const float4*)&PpowS[(size_t)r * P_SZ + p0];
    float4 lb = *(const float4*)&Lbar[p0];
    float d0r = wv.x * cv.x - wv.y * cv.y;
    float d0i = wv.x * cv.y + wv.y * cv.x;
    float d1r = wv.z * cv.z - wv.w * cv.w;
    float d1i = wv.z * cv.w + wv.w * cv.z;
    #pragma unroll
    for (int q = 0; q < 8; q++) {
        size_t o = (size_t)(m0 + q) * 1024 + (size_t)p0 * 2;
        ushort4 h = *(const ushort4*)&Xc[o];
        ushort4 l = *(const ushort4*)&Xc[MK2 + o];
        float xr0 = b2f(h.x) + b2f(l.x) + d0r;
        float xi0 = b2f(h.y) + b2f(l.y) + d0i;
        float xr1 = b2f(h.z) + b2f(l.z) + d1r;
        float xi1 = b2f(h.w) + b2f(l.w) + d1i;
        float t0r = d0r * lb.x - d0i * lb.y;
        float t0i = d0r * lb.y + d0i * lb.x;
        float t1r = d1r * lb.z - d1i * lb.w;
        float t1i = d1r * lb.w + d1i * lb.z;
        d0r = t0r; d0i = t0i; d1r = t1r; d1i = t1i;
        splitf(xr0, h.x, l.x);
        splitf(xi0, h.y, l.y);
        splitf(xr1, h.z, l.z);
        splitf(xi1, h.w, l.w);
        *(ushort4*)&Xc[o] = h;
        *(ushort4*)&Xc[MK2 + o] = l;
    }
}

// GEMM2: Y[m][h] = 2 * Xc[m][k'] * Cc[h][k'] over K'=1024 (re/im folded into K).
// Block 128x128, 4 waves of 64x64, 2-plane split.
__global__ __launch_bounds__(256, 2) void gemm2_k(const unsigned short* __restrict__ Xc,
                                                  const unsigned short* __restrict__ Cc,
                                                  float* __restrict__ Y) {
    __shared__ __align__(16) char smem[40960];
    unsigned short* sAh = (unsigned short*)smem;
    unsigned short* sAl = sAh + 128 * LDSP;
    unsigned short* sBh = sAl + 128 * LDSP;
    unsigned short* sBl = sBh + 128 * LDSP;
    const int tid = threadIdx.x;
    int g, nb;
    deswizzle4(blockIdx.x, g, nb);
    const int m0 = g * 128;
    const int n0 = nb * 128;
    const int lane = tid & 63, wv = tid >> 6;
    const int wm = wv & 1, wn = wv >> 1;
    const int lr = lane & 15, kg = lane >> 4;

    f32x4 acc[4][4];
    #pragma unroll
    for (int i = 0; i < 4; i++)
        #pragma unroll
        for (int j = 0; j < 4; j++) acc[i][j] = (f32x4)0.0f;

    const int srow = tid >> 2, sc8 = tid & 3;
    const int so0 = srow * LDSP + sc8 * 8;
    const int so1 = (srow + 64) * LDSP + sc8 * 8;

    const unsigned short* gAh = Xc + (size_t)(m0 + srow) * 1024 + sc8 * 8;
    const unsigned short* gAl = gAh + MK2;
    const unsigned short* gBh = Cc + (size_t)(n0 + srow) * 1024 + sc8 * 8;
    const unsigned short* gBl = gBh + KW;
    const size_t rs = (size_t)64 * 1024;

    int4 ah0 = *(const int4*)gAh, ah1 = *(const int4*)(gAh + rs);
    int4 al0 = *(const int4*)gAl, al1 = *(const int4*)(gAl + rs);
    int4 bh0 = *(const int4*)gBh, bh1 = *(const int4*)(gBh + rs);
    int4 bl0 = *(const int4*)gBl, bl1 = *(const int4*)(gBl + rs);

    for (int k0 = 0; k0 < 1024; k0 += 32) {
        __syncthreads();
        *(int4*)&sAh[so0] = ah0; *(int4*)&sAh[so1] = ah1;
        *(int4*)&sAl[so0] = al0; *(int4*)&sAl[so1] = al1;
        *(int4*)&sBh[so0] = bh0; *(int4*)&sBh[so1] = bh1;
        *(int4*)&sBl[so0] = bl0; *(int4*)&sBl[so1] = bl1;
        __syncthreads();
        if (k0 + 32 < 1024) {
            gAh += 32; gAl += 32; gBh += 32; gBl += 32;
            ah0 = *(const int4*)gAh; ah1 = *(const int4*)(gAh + rs);
            al0 = *(const int4*)gAl; al1 = *(const int4*)(gAl + rs);
            bh0 = *(const int4*)gBh; bh1 = *(const int4*)(gBh + rs);
            bl0 = *(const int4*)gBl; bl1 = *(const int4*)(gBl + rs);
        }

        bf16x8 fah[4], fal[4], fbh[4], fbl[4];
        #pragma unroll
        for (int mi = 0; mi < 4; mi++) {
            int off = (wm * 64 + mi * 16 + lr) * LDSP + kg * 8;
            fah[mi] = *(const bf16x8*)&sAh[off];
            fal[mi] = *(const bf16x8*)&sAl[off];
        }
        #pragma unroll
        for (int nj = 0; nj < 4; nj++) {
            int off = (wn * 64 + nj * 16 + lr) * LDSP + kg * 8;
            fbh[nj] = *(const bf16x8*)&sBh[off];
            fbl[nj] = *(const bf16x8*)&sBl[off];
        }
        #pragma unroll
        for (int mi = 0; mi < 4; mi++)
            #pragma unroll
            for (int nj = 0; nj < 4; nj++) {
                acc[mi][nj] = __builtin_amdgcn_mfma_f32_16x16x32_bf16(fah[mi], fbh[nj], acc[mi][nj], 0, 0, 0);
                acc[mi][nj] = __builtin_amdgcn_mfma_f32_16x16x32_bf16(fah[mi], fbl[nj], acc[mi][nj], 0, 0, 0);
                acc[mi][nj] = __builtin_amdgcn_mfma_f32_16x16x32_bf16(fal[mi], fbh[nj], acc[mi][nj], 0, 0, 0);
            }
    }
    #pragma unroll
    for (int mi = 0; mi < 4; mi++)
        #pragma unroll
        for (int nj = 0; nj < 4; nj++)
            #pragma unroll
            for (int r = 0; r < 4; r++) {
                int m = m0 + wm * 64 + mi * 16 + kg * 4 + r;
                int h = n0 + wn * 64 + nj * 16 + lr;
                Y[(size_t)m * H_SZ + h] = 2.0f * acc[mi][nj][r];
            }
}

extern "C" void kernel_launch(void* const* d_in, const int* in_sizes, int n_in,
                              void* d_out, int out_size, void* d_ws, size_t ws_size,
                              hipStream_t stream) {
    const float* lam_re   = (const float*)d_in[0];
    const float* lam_im   = (const float*)d_in[1];
    const float* Bre      = (const float*)d_in[2];
    const float* Bim      = (const float*)d_in[3];
    const float* Cre      = (const float*)d_in[4];
    const float* Cim      = (const float*)d_in[5];
    const float* log_step = (const float*)d_in[6];
    const float* U        = (const float*)d_in[7];
    float* Y = (float*)d_out;

    char* ws = (char*)d_ws;
    unsigned short* Xc = (unsigned short*)ws;                   // 134.2 MB (2 planes, k'-interleaved)
    ws += 2 * MK2 * sizeof(unsigned short);
    unsigned short* Upl = (unsigned short*)ws;                  // 67.1 MB (2 planes)
    ws += 2 * MH * sizeof(unsigned short);
    unsigned short* Wc = (unsigned short*)ws;                   // 2 MB
    ws += 2 * KW * sizeof(unsigned short);
    unsigned short* Cc = (unsigned short*)ws;                   // 2 MB
    ws += 2 * KW * sizeof(unsigned short);
    float2* Lbar = (float2*)ws;  ws += P_SZ * sizeof(float2);
    float2* AS   = (float2*)ws;  ws += P_SZ * sizeof(float2);
    float2* scale = (float2*)ws; ws += P_SZ * sizeof(float2);
    float2* carries = (float2*)ws;                              // 1 MB
    ws += (size_t)B_SZ * NCH * P_SZ * sizeof(float2);
    float2* PpowS = (float2*)ws;                                // 64 KB

    precompute_k<<<dim3((P_SZ + 255) / 256), dim3(256), 0, stream>>>(
        lam_re, lam_im, log_step, Lbar, AS, scale);
    ppows_k<<<dim3((16 * P_SZ) / 256), dim3(256), 0, stream>>>(Lbar, PpowS);
    bbar_k<<<dim3(PH / 256), dim3(256), 0, stream>>>(Bre, Bim, scale, Wc);
    csplit_k<<<dim3(PH / 256), dim3(256), 0, stream>>>(Cre, Cim, Cc);
    usplit_k<<<dim3((int)(MH / 4 / 256)), dim3(256), 0, stream>>>(U, Upl);
    gemm1_k<<<dim3((M_SZ / 128) * (1024 / 128)), dim3(256), 0, stream>>>(Upl, Wc, Lbar, Xc, carries);
    scanB_k<<<dim3((B_SZ * P_SZ) / 256), dim3(256), 0, stream>>>(carries, AS);
    xfix_k<<<dim3((int)(MK2 / 32 / 256)), dim3(256), 0, stream>>>(Xc, PpowS, Lbar, carries);
    gemm2_k<<<dim3((M_SZ / 128) * (H_SZ / 128)), dim3(256), 0, stream>>>(Xc, Cc, Y);
}

// Round 8
// 398.736 us; speedup vs baseline: 2.1530x; 1.0201x over previous
//
#include <hip/hip_runtime.h>

#define B_SZ 8
#define L_SZ 4096
#define H_SZ 512
#define P_SZ 512
#define M_SZ (B_SZ * L_SZ)      // 32768
#define NCH 32
#define CHUNK (L_SZ / NCH)      // 128
#define PH (P_SZ * H_SZ)
#define MH ((size_t)M_SZ * H_SZ)        // U plane elems
#define MK2 ((size_t)M_SZ * 1024)       // Xc plane elems (k' = 2*P)
#define KW ((size_t)1024 * 512)         // Wc / Cc plane elems
#define LDSP 40                          // padded LDS row stride in shorts (80B)

typedef __attribute__((ext_vector_type(8))) __bf16 bf16x8;
typedef __attribute__((ext_vector_type(4))) float f32x4;

// RNE fp32 -> bf16 split: x ~= hi + lo, each bf16. Error ~2^-18 relative.
__device__ __forceinline__ void splitf(float x, unsigned short& h, unsigned short& l) {
    unsigned u = __float_as_uint(x);
    unsigned hr = (u + 0x7fffu + ((u >> 16) & 1u)) >> 16;
    h = (unsigned short)hr;
    float lo = x - __uint_as_float(hr << 16);       // exact (Sterbenz)
    unsigned ul = __float_as_uint(lo);
    l = (unsigned short)((ul + 0x7fffu + ((ul >> 16) & 1u)) >> 16);
}

__device__ __forceinline__ float b2f(unsigned short s) {
    return __uint_as_float(((unsigned)s) << 16);
}

__global__ void precompute_k(const float* __restrict__ lam_re,
                             const float* __restrict__ lam_im,
                             const float* __restrict__ log_step,
                             float2* __restrict__ Lbar,
                             float2* __restrict__ AS,
                             float2* __restrict__ scale) {
    int p = blockIdx.x * blockDim.x + threadIdx.x;
    if (p >= P_SZ) return;
    float lr = lam_re[p], li = lam_im[p];
    float dt = expf(log_step[p]);
    float zr = lr * dt, zi = li * dt;
    float er = expf(zr);
    float ar = er * cosf(zi), ai = er * sinf(zi);
    Lbar[p] = make_float2(ar, ai);
    float nr = ar - 1.0f, ni = ai;
    float d2 = lr * lr + li * li;
    scale[p] = make_float2((nr * lr + ni * li) / d2, (ni * lr - nr * li) / d2);
    float xr = ar, xi = ai;
    #pragma unroll
    for (int i = 0; i < 7; i++) {      // A^128 via squarings
        float tr = xr * xr - xi * xi;
        float ti = 2.0f * xr * xi;
        xr = tr; xi = ti;
    }
    AS[p] = make_float2(xr, xi);
}

// PpowS[r][p] = Lbar[p]^(8r+1), r in [0,16)  (64 KB, stays L2-hot)
__global__ void ppows_k(const float2* __restrict__ Lbar,
                        float2* __restrict__ PpowS) {
    int idx = blockIdx.x * blockDim.x + threadIdx.x;   // r*P + p
    if (idx >= 16 * P_SZ) return;
    int p = idx & (P_SZ - 1);
    int r = idx >> 9;
    int e = 8 * r + 1;                                  // 1..121
    float2 base = Lbar[p];
    float rr = 1.0f, ri = 0.0f;
    float br = base.x, bi = base.y;
    #pragma unroll
    for (int bit = 0; bit < 7; bit++) {
        if ((e >> bit) & 1) {
            float nr = rr * br - ri * bi;
            float ni = rr * bi + ri * br;
            rr = nr; ri = ni;
        }
        float sr = br * br - bi * bi;
        float si = 2.0f * br * bi;
        br = sr; bi = si;
    }
    PpowS[idx] = make_float2(rr, ri);
}

// B_bar = scale*(Bre + i Bim). Wc rows n'=2p -> w_re row, n'=2p+1 -> w_im row,
// 2 planes [hi | lo], each [1024][512].
__global__ void bbar_k(const float* __restrict__ Bre,
                       const float* __restrict__ Bim,
                       const float2* __restrict__ scale,
                       unsigned short* __restrict__ Wc) {
    int idx = blockIdx.x * blockDim.x + threadIdx.x;
    if (idx >= PH) return;
    int p = idx / H_SZ;
    int h = idx - p * H_SZ;
    float2 s = scale[p];
    float br = Bre[idx], bi = Bim[idx];
    float wr = s.x * br - s.y * bi;
    float wi = s.x * bi + s.y * br;
    unsigned short hh, ll;
    splitf(wr, hh, ll);
    Wc[(size_t)(2 * p) * H_SZ + h] = hh;
    Wc[KW + (size_t)(2 * p) * H_SZ + h] = ll;
    splitf(wi, hh, ll);
    Wc[(size_t)(2 * p + 1) * H_SZ + h] = hh;
    Wc[KW + (size_t)(2 * p + 1) * H_SZ + h] = ll;
}

// Cc planes [hi | lo], each [512][1024]: k'=2p -> split(Cre), k'=2p+1 -> split(-Cim)
__global__ void csplit_k(const float* __restrict__ Cre,
                         const float* __restrict__ Cim,
                         unsigned short* __restrict__ Cc) {
    int idx = blockIdx.x * blockDim.x + threadIdx.x;   // h*P + p
    if (idx >= PH) return;
    int hrow = idx / P_SZ;
    int p = idx - hrow * P_SZ;
    unsigned short ah, al, bh, bl;
    splitf(Cre[idx], ah, al);
    splitf(-Cim[idx], bh, bl);
    ushort2 hi; hi.x = ah; hi.y = bh;
    ushort2 lo; lo.x = al; lo.y = bl;
    *(ushort2*)&Cc[(size_t)hrow * 1024 + 2 * p] = hi;
    *(ushort2*)&Cc[KW + (size_t)hrow * 1024 + 2 * p] = lo;
}

// U -> 2 bf16 planes [uh|ul], done ONCE
__global__ __launch_bounds__(256) void usplit_k(const float* __restrict__ U,
                                                unsigned short* __restrict__ Upl) {
    size_t i4 = (size_t)blockIdx.x * 256 + threadIdx.x;
    float4 v = *(const float4*)&U[i4 * 4];
    ushort4 h, l;
    splitf(v.x, h.x, l.x);
    splitf(v.y, h.y, l.y);
    splitf(v.z, h.z, l.z);
    splitf(v.w, h.w, l.w);
    *(ushort4*)&Upl[i4 * 4] = h;
    *(ushort4*)&Upl[MH + i4 * 4] = l;
}

// same-m blocks share an XCD and a dispatch window (L2 temporal locality)
__device__ __forceinline__ void deswizzle8(int bid, int& m, int& n) {
    int xcd = bid & 7;
    n = (bid >> 3) & 7;
    m = ((bid >> 6) << 3) + xcd;
}
__device__ __forceinline__ void deswizzle4(int bid, int& m, int& n) {
    int xcd = bid & 7;
    n = (bid >> 3) & 3;
    m = ((bid >> 5) << 3) + xcd;
}

// GEMM1: Bu[m][n'=1024] = U[m][k] * Wc[n'][k], 2-plane split (hh+hl+lh).
// Block 128x128(n'), 4 waves of 64x64. Fused local chunk scan + plane write.
// R3-VERBATIM (harness-verified). Quarantined variants (all failed on HW):
// DMA staging (R4), XOR-swizzle LDS (R4/R5), 2-phase scan (R4/R5),
// parallel quarter-scan w/ 66KB static LDS (R6/R7). Any future scan change
// must be an isolated delta and keep static LDS <= 65536 B.
__global__ __launch_bounds__(256, 2) void gemm1_k(const unsigned short* __restrict__ Upl,
                                                  const unsigned short* __restrict__ Wc,
                                                  const float2* __restrict__ Lbar,
                                                  unsigned short* __restrict__ Xc,
                                                  float2* __restrict__ carries) {
    __shared__ __align__(16) char smem[65536];
    unsigned short* sAh = (unsigned short*)smem;        // [128][LDSP]
    unsigned short* sAl = sAh + 128 * LDSP;
    unsigned short* sBh = sAl + 128 * LDSP;
    unsigned short* sBl = sBh + 128 * LDSP;             // 40960 B
    const int tid = threadIdx.x;
    int g, nb;
    deswizzle8(blockIdx.x, g, nb);
    const int m0 = g * 128;
    const int n0 = nb * 128;                            // n' base
    const int lane = tid & 63, wv = tid >> 6;
    const int wm = wv & 1, wn = wv >> 1;
    const int lr = lane & 15, kg = lane >> 4;

    f32x4 acc[4][4];
    #pragma unroll
    for (int i = 0; i < 4; i++)
        #pragma unroll
        for (int j = 0; j < 4; j++) acc[i][j] = (f32x4)0.0f;

    const int srow = tid >> 2, sc8 = tid & 3;
    const int so0 = srow * LDSP + sc8 * 8;
    const int so1 = (srow + 64) * LDSP + sc8 * 8;

    const unsigned short* gAh = Upl + (size_t)(m0 + srow) * H_SZ + sc8 * 8;
    const unsigned short* gAl = gAh + MH;
    const unsigned short* gBh = Wc + (size_t)(n0 + srow) * H_SZ + sc8 * 8;
    const unsigned short* gBl = gBh + KW;
    const size_t rs = (size_t)64 * H_SZ;

    int4 ah0 = *(const int4*)gAh, ah1 = *(const int4*)(gAh + rs);
    int4 al0 = *(const int4*)gAl, al1 = *(const int4*)(gAl + rs);
    int4 bh0 = *(const int4*)gBh, bh1 = *(const int4*)(gBh + rs);
    int4 bl0 = *(const int4*)gBl, bl1 = *(const int4*)(gBl + rs);

    for (int k0 = 0; k0 < H_SZ; k0 += 32) {
        __syncthreads();
        *(int4*)&sAh[so0] = ah0; *(int4*)&sAh[so1] = ah1;
        *(int4*)&sAl[so0] = al0; *(int4*)&sAl[so1] = al1;
        *(int4*)&sBh[so0] = bh0; *(int4*)&sBh[so1] = bh1;
        *(int4*)&sBl[so0] = bl0; *(int4*)&sBl[so1] = bl1;
        __syncthreads();
        if (k0 + 32 < H_SZ) {
            gAh += 32; gAl += 32; gBh += 32; gBl += 32;
            ah0 = *(const int4*)gAh; ah1 = *(const int4*)(gAh + rs);
            al0 = *(const int4*)gAl; al1 = *(const int4*)(gAl + rs);
            bh0 = *(const int4*)gBh; bh1 = *(const int4*)(gBh + rs);
            bl0 = *(const int4*)gBl; bl1 = *(const int4*)(gBl + rs);
        }

        bf16x8 fah[4], fal[4], fbh[4], fbl[4];
        #pragma unroll
        for (int mi = 0; mi < 4; mi++) {
            int off = (wm * 64 + mi * 16 + lr) * LDSP + kg * 8;
            fah[mi] = *(const bf16x8*)&sAh[off];
            fal[mi] = *(const bf16x8*)&sAl[off];
        }
        #pragma unroll
        for (int nj = 0; nj < 4; nj++) {
            int off = (wn * 64 + nj * 16 + lr) * LDSP + kg * 8;
            fbh[nj] = *(const bf16x8*)&sBh[off];
            fbl[nj] = *(const bf16x8*)&sBl[off];
        }
        #pragma unroll
        for (int mi = 0; mi < 4; mi++)
            #pragma unroll
            for (int nj = 0; nj < 4; nj++) {
                acc[mi][nj] = __builtin_amdgcn_mfma_f32_16x16x32_bf16(fah[mi], fbh[nj], acc[mi][nj], 0, 0, 0);
                acc[mi][nj] = __builtin_amdgcn_mfma_f32_16x16x32_bf16(fah[mi], fbl[nj], acc[mi][nj], 0, 0, 0);
                acc[mi][nj] = __builtin_amdgcn_mfma_f32_16x16x32_bf16(fal[mi], fbh[nj], acc[mi][nj], 0, 0, 0);
            }
    }

    // ---- epilogue: local chunk scan in LDS (reuses staging LDS) ----
    __syncthreads();
    float* xsf = (float*)smem;                 // [128 t][128 n'] = 64KB
    #pragma unroll
    for (int mi = 0; mi < 4; mi++)
        #pragma unroll
        for (int nj = 0; nj < 4; nj++)
            #pragma unroll
            for (int r = 0; r < 4; r++) {
                int t = wm * 64 + mi * 16 + kg * 4 + r;
                int np = wn * 64 + nj * 16 + lr;
                xsf[t * 128 + np] = acc[mi][nj][r];
            }
    __syncthreads();
    if (tid < 64) {
        float2* xs2 = (float2*)smem;           // [128 t][64 p]
        float2 A = Lbar[nb * 64 + tid];
        float xr = 0.f, xi = 0.f;
        for (int t = 0; t < CHUNK; t++) {
            float2 v = xs2[t * 64 + tid];
            float nr = fmaf(A.x, xr, fmaf(-A.y, xi, v.x));
            float ni = fmaf(A.x, xi, fmaf(A.y, xr, v.y));
            xr = nr; xi = ni;
            xs2[t * 64 + tid] = make_float2(xr, xi);
        }
        carries[(size_t)g * P_SZ + nb * 64 + tid] = make_float2(xr, xi);
    }
    __syncthreads();
    const float4* xs4 = (const float4*)smem;   // [128][32] (re,im,re,im)
    #pragma unroll
    for (int it = 0; it < 16; it++) {
        int lin = tid + it * 256;              // 4096
        int row = lin >> 5;
        int c4  = lin & 31;
        float4 v = xs4[lin];
        ushort4 h4, l4;
        splitf(v.x, h4.x, l4.x);
        splitf(v.y, h4.y, l4.y);
        splitf(v.z, h4.z, l4.z);
        splitf(v.w, h4.w, l4.w);
        size_t o = (size_t)(m0 + row) * 1024 + n0 + c4 * 4;
        *(ushort4*)&Xc[o] = h4;
        *(ushort4*)&Xc[MK2 + o] = l4;
    }
}

__global__ void scanB_k(float2* __restrict__ carries,
                        const float2* __restrict__ AS) {
    int tid = blockIdx.x * blockDim.x + threadIdx.x;
    int p = tid & (P_SZ - 1);
    int b = tid / P_SZ;
    float2 A = AS[p];
    float cr = 0.f, ci = 0.f;
    for (int c = 0; c < NCH; c++) {
        int idx = (b * NCH + c) * P_SZ + p;
        float2 t = carries[idx];
        carries[idx] = make_float2(cr, ci);
        float nr = fmaf(A.x, cr, fmaf(-A.y, ci, t.x));
        float ni = fmaf(A.x, ci, fmaf(A.y, cr, t.y));
        cr = nr; ci = ni;
    }
}

// In-place carry fix-up on the interleaved X planes:
// x_global = x_local + Lbar^(t+1)*carry  (hi+lo reconstruct is exact to 2^-18)
__global__ __launch_bounds__(256) void xfix_k(unsigned short* __restrict__ Xc,
                                              const float2* __restrict__ PpowS,
                                              const float2* __restrict__ Lbar,
                                              const float2* __restrict__ carries) {
    int t = blockIdx.x * 256 + threadIdx.x;
    int pc = t & 255;                  // complex pair p0=2pc, p0+1 -> k' = 4pc..4pc+3
    int rb = t >> 8;                   // 8-row block
    int p0 = pc * 2;
    int m0 = rb * 8;
    int g = m0 >> 7;                   // chunk
    int r = (m0 & 127) >> 3;           // stepped-power row
    float4 cv = *(const float4*)&carries[(size_t)g * P_SZ + p0];
    float4 wv = *(const float4*)&PpowS[(size_t)r * P_SZ + p0];
    float4 lb = *(const float4*)&Lbar[p0];
    float d0r = wv.x * cv.x - wv.y * cv.y;
    float d0i = wv.x * cv.y + wv.y * cv.x;
    float d1r = wv.z * cv.z - wv.w * cv.w;
    float d1i = wv.z * cv.w + wv.w * cv.z;
    #pragma unroll
    for (int q = 0; q < 8; q++) {
        size_t o = (size_t)(m0 + q) * 1024 + (size_t)p0 * 2;
        ushort4 h = *(const ushort4*)&Xc[o];
        ushort4 l = *(const ushort4*)&Xc[MK2 + o];
        float xr0 = b2f(h.x) + b2f(l.x) + d0r;
        float xi0 = b2f(h.y) + b2f(l.y) + d0i;
        float xr1 = b2f(h.z) + b2f(l.z) + d1r;
        float xi1 = b2f(h.w) + b2f(l.w) + d1i;
        float t0r = d0r * lb.x - d0i * lb.y;
        float t0i = d0r * lb.y + d0i * lb.x;
        float t1r = d1r * lb.z - d1i * lb.w;
        float t1i = d1r * lb.w + d1i * lb.z;
        d0r = t0r; d0i = t0i; d1r = t1r; d1i = t1i;
        splitf(xr0, h.x, l.x);
        splitf(xi0, h.y, l.y);
        splitf(xr1, h.z, l.z);
        splitf(xi1, h.w, l.w);
        *(ushort4*)&Xc[o] = h;
        *(ushort4*)&Xc[MK2 + o] = l;
    }
}

// GEMM2: Y[m][h] = 2 * Xc[m][k'] * Cc[h][k'] over K'=1024 (re/im folded into K).
// Block 128x128, 4 waves of 64x64, 2-plane split. R3-VERBATIM.
__global__ __launch_bounds__(256, 2) void gemm2_k(const unsigned short* __restrict__ Xc,
                                                  const unsigned short* __restrict__ Cc,
                                                  float* __restrict__ Y) {
    __shared__ __align__(16) char smem[40960];
    unsigned short* sAh = (unsigned short*)smem;
    unsigned short* sAl = sAh + 128 * LDSP;
    unsigned short* sBh = sAl + 128 * LDSP;
    unsigned short* sBl = sBh + 128 * LDSP;
    const int tid = threadIdx.x;
    int g, nb;
    deswizzle4(blockIdx.x, g, nb);
    const int m0 = g * 128;
    const int n0 = nb * 128;
    const int lane = tid & 63, wv = tid >> 6;
    const int wm = wv & 1, wn = wv >> 1;
    const int lr = lane & 15, kg = lane >> 4;

    f32x4 acc[4][4];
    #pragma unroll
    for (int i = 0; i < 4; i++)
        #pragma unroll
        for (int j = 0; j < 4; j++) acc[i][j] = (f32x4)0.0f;

    const int srow = tid >> 2, sc8 = tid & 3;
    const int so0 = srow * LDSP + sc8 * 8;
    const int so1 = (srow + 64) * LDSP + sc8 * 8;

    const unsigned short* gAh = Xc + (size_t)(m0 + srow) * 1024 + sc8 * 8;
    const unsigned short* gAl = gAh + MK2;
    const unsigned short* gBh = Cc + (size_t)(n0 + srow) * 1024 + sc8 * 8;
    const unsigned short* gBl = gBh + KW;
    const size_t rs = (size_t)64 * 1024;

    int4 ah0 = *(const int4*)gAh, ah1 = *(const int4*)(gAh + rs);
    int4 al0 = *(const int4*)gAl, al1 = *(const int4*)(gAl + rs);
    int4 bh0 = *(const int4*)gBh, bh1 = *(const int4*)(gBh + rs);
    int4 bl0 = *(const int4*)gBl, bl1 = *(const int4*)(gBl + rs);

    for (int k0 = 0; k0 < 1024; k0 += 32) {
        __syncthreads();
        *(int4*)&sAh[so0] = ah0; *(int4*)&sAh[so1] = ah1;
        *(int4*)&sAl[so0] = al0; *(int4*)&sAl[so1] = al1;
        *(int4*)&sBh[so0] = bh0; *(int4*)&sBh[so1] = bh1;
        *(int4*)&sBl[so0] = bl0; *(int4*)&sBl[so1] = bl1;
        __syncthreads();
        if (k0 + 32 < 1024) {
            gAh += 32; gAl += 32; gBh += 32; gBl += 32;
            ah0 = *(const int4*)gAh; ah1 = *(const int4*)(gAh + rs);
            al0 = *(const int4*)gAl; al1 = *(const int4*)(gAl + rs);
            bh0 = *(const int4*)gBh; bh1 = *(const int4*)(gBh + rs);
            bl0 = *(const int4*)gBl; bl1 = *(const int4*)(gBl + rs);
        }

        bf16x8 fah[4], fal[4], fbh[4], fbl[4];
        #pragma unroll
        for (int mi = 0; mi < 4; mi++) {
            int off = (wm * 64 + mi * 16 + lr) * LDSP + kg * 8;
            fah[mi] = *(const bf16x8*)&sAh[off];
            fal[mi] = *(const bf16x8*)&sAl[off];
        }
        #pragma unroll
        for (int nj = 0; nj < 4; nj++) {
            int off = (wn * 64 + nj * 16 + lr) * LDSP + kg * 8;
            fbh[nj] = *(const bf16x8*)&sBh[off];
            fbl[nj] = *(const bf16x8*)&sBl[off];
        }
        #pragma unroll
        for (int mi = 0; mi < 4; mi++)
            #pragma unroll
            for (int nj = 0; nj < 4; nj++) {
                acc[mi][nj] = __builtin_amdgcn_mfma_f32_16x16x32_bf16(fah[mi], fbh[nj], acc[mi][nj], 0, 0, 0);
                acc[mi][nj] = __builtin_amdgcn_mfma_f32_16x16x32_bf16(fah[mi], fbl[nj], acc[mi][nj], 0, 0, 0);
                acc[mi][nj] = __builtin_amdgcn_mfma_f32_16x16x32_bf16(fal[mi], fbh[nj], acc[mi][nj], 0, 0, 0);
            }
    }
    #pragma unroll
    for (int mi = 0; mi < 4; mi++)
        #pragma unroll
        for (int nj = 0; nj < 4; nj++)
            #pragma unroll
            for (int r = 0; r < 4; r++) {
                int m = m0 + wm * 64 + mi * 16 + kg * 4 + r;
                int h = n0 + wn * 64 + nj * 16 + lr;
                Y[(size_t)m * H_SZ + h] = 2.0f * acc[mi][nj][r];
            }
}

extern "C" void kernel_launch(void* const* d_in, const int* in_sizes, int n_in,
                              void* d_out, int out_size, void* d_ws, size_t ws_size,
                              hipStream_t stream) {
    const float* lam_re   = (const float*)d_in[0];
    const float* lam_im   = (const float*)d_in[1];
    const float* Bre      = (const float*)d_in[2];
    const float* Bim      = (const float*)d_in[3];
    const float* Cre      = (const float*)d_in[4];
    const float* Cim      = (const float*)d_in[5];
    const float* log_step = (const float*)d_in[6];
    const float* U        = (const float*)d_in[7];
    float* Y = (float*)d_out;

    char* ws = (char*)d_ws;
    unsigned short* Xc = (unsigned short*)ws;                   // 134.2 MB (2 planes, k'-interleaved)
    ws += 2 * MK2 * sizeof(unsigned short);
    unsigned short* Upl = (unsigned short*)ws;                  // 67.1 MB (2 planes)
    ws += 2 * MH * sizeof(unsigned short);
    unsigned short* Wc = (unsigned short*)ws;                   // 2 MB
    ws += 2 * KW * sizeof(unsigned short);
    unsigned short* Cc = (unsigned short*)ws;                   // 2 MB
    ws += 2 * KW * sizeof(unsigned short);
    float2* Lbar = (float2*)ws;  ws += P_SZ * sizeof(float2);
    float2* AS   = (float2*)ws;  ws += P_SZ * sizeof(float2);
    float2* scale = (float2*)ws; ws += P_SZ * sizeof(float2);
    float2* carries = (float2*)ws;                              // 1 MB
    ws += (size_t)B_SZ * NCH * P_SZ * sizeof(float2);
    float2* PpowS = (float2*)ws;                                // 64 KB

    precompute_k<<<dim3((P_SZ + 255) / 256), dim3(256), 0, stream>>>(
        lam_re, lam_im, log_step, Lbar, AS, scale);
    ppows_k<<<dim3((16 * P_SZ) / 256), dim3(256), 0, stream>>>(Lbar, PpowS);
    bbar_k<<<dim3(PH / 256), dim3(256), 0, stream>>>(Bre, Bim, scale, Wc);
    csplit_k<<<dim3(PH / 256), dim3(256), 0, stream>>>(Cre, Cim, Cc);
    usplit_k<<<dim3((int)(MH / 4 / 256)), dim3(256), 0, stream>>>(U, Upl);
    gemm1_k<<<dim3((M_SZ / 128) * (1024 / 128)), dim3(256), 0, stream>>>(Upl, Wc, Lbar, Xc, carries);
    scanB_k<<<dim3((B_SZ * P_SZ) / 256), dim3(256), 0, stream>>>(carries, AS);
    xfix_k<<<dim3((int)(MK2 / 32 / 256)), dim3(256), 0, stream>>>(Xc, PpowS, Lbar, carries);
    gemm2_k<<<dim3((M_SZ / 128) * (H_SZ / 128)), dim3(256), 0, stream>>>(Xc, Cc, Y);
}

// Round 9
// 392.291 us; speedup vs baseline: 2.1884x; 1.0164x over previous
//
#include <hip/hip_runtime.h>

#define B_SZ 8
#define L_SZ 4096
#define H_SZ 512
#define P_SZ 512
#define M_SZ (B_SZ * L_SZ)      // 32768
#define NCH 32
#define CHUNK (L_SZ / NCH)      // 128
#define PH (P_SZ * H_SZ)
#define MK2 ((size_t)M_SZ * 1024)       // Xc plane elems (k' = 2*P)
#define KW ((size_t)1024 * 512)         // Wc / Cc plane elems
#define LDSP 40                          // padded LDS row stride in shorts (80B)

typedef __attribute__((ext_vector_type(8))) __bf16 bf16x8;
typedef __attribute__((ext_vector_type(4))) float f32x4;

// RNE fp32 -> bf16 split: x ~= hi + lo, each bf16. Error ~2^-18 relative.
__device__ __forceinline__ void splitf(float x, unsigned short& h, unsigned short& l) {
    unsigned u = __float_as_uint(x);
    unsigned hr = (u + 0x7fffu + ((u >> 16) & 1u)) >> 16;
    h = (unsigned short)hr;
    float lo = x - __uint_as_float(hr << 16);       // exact (Sterbenz)
    unsigned ul = __float_as_uint(lo);
    l = (unsigned short)((ul + 0x7fffu + ((ul >> 16) & 1u)) >> 16);
}

__device__ __forceinline__ float b2f(unsigned short s) {
    return __uint_as_float(((unsigned)s) << 16);
}

__global__ void precompute_k(const float* __restrict__ lam_re,
                             const float* __restrict__ lam_im,
                             const float* __restrict__ log_step,
                             float2* __restrict__ Lbar,
                             float2* __restrict__ AS,
                             float2* __restrict__ scale) {
    int p = blockIdx.x * blockDim.x + threadIdx.x;
    if (p >= P_SZ) return;
    float lr = lam_re[p], li = lam_im[p];
    float dt = expf(log_step[p]);
    float zr = lr * dt, zi = li * dt;
    float er = expf(zr);
    float ar = er * cosf(zi), ai = er * sinf(zi);
    Lbar[p] = make_float2(ar, ai);
    float nr = ar - 1.0f, ni = ai;
    float d2 = lr * lr + li * li;
    scale[p] = make_float2((nr * lr + ni * li) / d2, (ni * lr - nr * li) / d2);
    float xr = ar, xi = ai;
    #pragma unroll
    for (int i = 0; i < 7; i++) {      // A^128 via squarings
        float tr = xr * xr - xi * xi;
        float ti = 2.0f * xr * xi;
        xr = tr; xi = ti;
    }
    AS[p] = make_float2(xr, xi);
}

// PpowS[r][p] = Lbar[p]^(8r+1), r in [0,16)  (64 KB, stays L2-hot)
__global__ void ppows_k(const float2* __restrict__ Lbar,
                        float2* __restrict__ PpowS) {
    int idx = blockIdx.x * blockDim.x + threadIdx.x;   // r*P + p
    if (idx >= 16 * P_SZ) return;
    int p = idx & (P_SZ - 1);
    int r = idx >> 9;
    int e = 8 * r + 1;                                  // 1..121
    float2 base = Lbar[p];
    float rr = 1.0f, ri = 0.0f;
    float br = base.x, bi = base.y;
    #pragma unroll
    for (int bit = 0; bit < 7; bit++) {
        if ((e >> bit) & 1) {
            float nr = rr * br - ri * bi;
            float ni = rr * bi + ri * br;
            rr = nr; ri = ni;
        }
        float sr = br * br - bi * bi;
        float si = 2.0f * br * bi;
        br = sr; bi = si;
    }
    PpowS[idx] = make_float2(rr, ri);
}

// B_bar = scale*(Bre + i Bim). Wc rows n'=2p -> w_re row, n'=2p+1 -> w_im row,
// 2 planes [hi | lo], each [1024][512].
__global__ void bbar_k(const float* __restrict__ Bre,
                       const float* __restrict__ Bim,
                       const float2* __restrict__ scale,
                       unsigned short* __restrict__ Wc) {
    int idx = blockIdx.x * blockDim.x + threadIdx.x;
    if (idx >= PH) return;
    int p = idx / H_SZ;
    int h = idx - p * H_SZ;
    float2 s = scale[p];
    float br = Bre[idx], bi = Bim[idx];
    float wr = s.x * br - s.y * bi;
    float wi = s.x * bi + s.y * br;
    unsigned short hh, ll;
    splitf(wr, hh, ll);
    Wc[(size_t)(2 * p) * H_SZ + h] = hh;
    Wc[KW + (size_t)(2 * p) * H_SZ + h] = ll;
    splitf(wi, hh, ll);
    Wc[(size_t)(2 * p + 1) * H_SZ + h] = hh;
    Wc[KW + (size_t)(2 * p + 1) * H_SZ + h] = ll;
}

// Cc planes [hi | lo], each [512][1024]: k'=2p -> split(Cre), k'=2p+1 -> split(-Cim)
__global__ void csplit_k(const float* __restrict__ Cre,
                         const float* __restrict__ Cim,
                         unsigned short* __restrict__ Cc) {
    int idx = blockIdx.x * blockDim.x + threadIdx.x;   // h*P + p
    if (idx >= PH) return;
    int hrow = idx / P_SZ;
    int p = idx - hrow * P_SZ;
    unsigned short ah, al, bh, bl;
    splitf(Cre[idx], ah, al);
    splitf(-Cim[idx], bh, bl);
    ushort2 hi; hi.x = ah; hi.y = bh;
    ushort2 lo; lo.x = al; lo.y = bl;
    *(ushort2*)&Cc[(size_t)hrow * 1024 + 2 * p] = hi;
    *(ushort2*)&Cc[KW + (size_t)hrow * 1024 + 2 * p] = lo;
}

// same-m blocks share an XCD and a dispatch window (L2 temporal locality)
__device__ __forceinline__ void deswizzle8(int bid, int& m, int& n) {
    int xcd = bid & 7;
    n = (bid >> 3) & 7;
    m = ((bid >> 6) << 3) + xcd;
}
__device__ __forceinline__ void deswizzle4(int bid, int& m, int& n) {
    int xcd = bid & 7;
    n = (bid >> 3) & 3;
    m = ((bid >> 5) << 3) + xcd;
}

// GEMM1: Bu[m][n'=1024] = U[m][k] * Wc[n'][k], 2-plane split (hh+hl+lh).
// U is read DIRECTLY as fp32 and split in staging (usplit pass eliminated:
// identical bytes of traffic, bit-identical splitf results, -45us pass).
// Block 128x128(n'), 4 waves of 64x64, padded-LDS staging. Scan epilogue
// R3/R8-VERBATIM (quarantine: DMA/XOR-swz/2-phase/parallel-scan all failed
// on HW; static LDS must stay <= 65536 B).
__global__ __launch_bounds__(256, 2) void gemm1_k(const float* __restrict__ U,
                                                  const unsigned short* __restrict__ Wc,
                                                  const float2* __restrict__ Lbar,
                                                  unsigned short* __restrict__ Xc,
                                                  float2* __restrict__ carries) {
    __shared__ __align__(16) char smem[65536];
    unsigned short* sAh = (unsigned short*)smem;        // [128][LDSP]
    unsigned short* sAl = sAh + 128 * LDSP;
    unsigned short* sBh = sAl + 128 * LDSP;
    unsigned short* sBl = sBh + 128 * LDSP;             // 40960 B
    const int tid = threadIdx.x;
    int g, nb;
    deswizzle8(blockIdx.x, g, nb);
    const int m0 = g * 128;
    const int n0 = nb * 128;                            // n' base
    const int lane = tid & 63, wv = tid >> 6;
    const int wm = wv & 1, wn = wv >> 1;
    const int lr = lane & 15, kg = lane >> 4;

    f32x4 acc[4][4];
    #pragma unroll
    for (int i = 0; i < 4; i++)
        #pragma unroll
        for (int j = 0; j < 4; j++) acc[i][j] = (f32x4)0.0f;

    const int srow = tid >> 2, sc8 = tid & 3;
    const int so0 = srow * LDSP + sc8 * 8;
    const int so1 = (srow + 64) * LDSP + sc8 * 8;

    const float* gU = U + (size_t)(m0 + srow) * H_SZ + sc8 * 8;
    const unsigned short* gBh = Wc + (size_t)(n0 + srow) * H_SZ + sc8 * 8;
    const unsigned short* gBl = gBh + KW;
    const size_t rsf = (size_t)64 * H_SZ;
    const size_t rs = (size_t)64 * H_SZ;

    float4 u00 = *(const float4*)gU;
    float4 u01 = *(const float4*)(gU + 4);
    float4 u10 = *(const float4*)(gU + rsf);
    float4 u11 = *(const float4*)(gU + rsf + 4);
    int4 bh0 = *(const int4*)gBh, bh1 = *(const int4*)(gBh + rs);
    int4 bl0 = *(const int4*)gBl, bl1 = *(const int4*)(gBl + rs);

    for (int k0 = 0; k0 < H_SZ; k0 += 32) {
        __syncthreads();
        {
            ushort4 h, l;
            splitf(u00.x, h.x, l.x); splitf(u00.y, h.y, l.y);
            splitf(u00.z, h.z, l.z); splitf(u00.w, h.w, l.w);
            *(ushort4*)&sAh[so0] = h; *(ushort4*)&sAl[so0] = l;
            splitf(u01.x, h.x, l.x); splitf(u01.y, h.y, l.y);
            splitf(u01.z, h.z, l.z); splitf(u01.w, h.w, l.w);
            *(ushort4*)&sAh[so0 + 4] = h; *(ushort4*)&sAl[so0 + 4] = l;
            splitf(u10.x, h.x, l.x); splitf(u10.y, h.y, l.y);
            splitf(u10.z, h.z, l.z); splitf(u10.w, h.w, l.w);
            *(ushort4*)&sAh[so1] = h; *(ushort4*)&sAl[so1] = l;
            splitf(u11.x, h.x, l.x); splitf(u11.y, h.y, l.y);
            splitf(u11.z, h.z, l.z); splitf(u11.w, h.w, l.w);
            *(ushort4*)&sAh[so1 + 4] = h; *(ushort4*)&sAl[so1 + 4] = l;
        }
        *(int4*)&sBh[so0] = bh0; *(int4*)&sBh[so1] = bh1;
        *(int4*)&sBl[so0] = bl0; *(int4*)&sBl[so1] = bl1;
        __syncthreads();
        if (k0 + 32 < H_SZ) {
            gU += 32; gBh += 32; gBl += 32;
            u00 = *(const float4*)gU;
            u01 = *(const float4*)(gU + 4);
            u10 = *(const float4*)(gU + rsf);
            u11 = *(const float4*)(gU + rsf + 4);
            bh0 = *(const int4*)gBh; bh1 = *(const int4*)(gBh + rs);
            bl0 = *(const int4*)gBl; bl1 = *(const int4*)(gBl + rs);
        }

        bf16x8 fah[4], fal[4], fbh[4], fbl[4];
        #pragma unroll
        for (int mi = 0; mi < 4; mi++) {
            int off = (wm * 64 + mi * 16 + lr) * LDSP + kg * 8;
            fah[mi] = *(const bf16x8*)&sAh[off];
            fal[mi] = *(const bf16x8*)&sAl[off];
        }
        #pragma unroll
        for (int nj = 0; nj < 4; nj++) {
            int off = (wn * 64 + nj * 16 + lr) * LDSP + kg * 8;
            fbh[nj] = *(const bf16x8*)&sBh[off];
            fbl[nj] = *(const bf16x8*)&sBl[off];
        }
        #pragma unroll
        for (int mi = 0; mi < 4; mi++)
            #pragma unroll
            for (int nj = 0; nj < 4; nj++) {
                acc[mi][nj] = __builtin_amdgcn_mfma_f32_16x16x32_bf16(fah[mi], fbh[nj], acc[mi][nj], 0, 0, 0);
                acc[mi][nj] = __builtin_amdgcn_mfma_f32_16x16x32_bf16(fah[mi], fbl[nj], acc[mi][nj], 0, 0, 0);
                acc[mi][nj] = __builtin_amdgcn_mfma_f32_16x16x32_bf16(fal[mi], fbh[nj], acc[mi][nj], 0, 0, 0);
            }
    }

    // ---- epilogue: local chunk scan in LDS (reuses staging LDS) ----
    __syncthreads();
    float* xsf = (float*)smem;                 // [128 t][128 n'] = 64KB
    #pragma unroll
    for (int mi = 0; mi < 4; mi++)
        #pragma unroll
        for (int nj = 0; nj < 4; nj++)
            #pragma unroll
            for (int r = 0; r < 4; r++) {
                int t = wm * 64 + mi * 16 + kg * 4 + r;
                int np = wn * 64 + nj * 16 + lr;
                xsf[t * 128 + np] = acc[mi][nj][r];
            }
    __syncthreads();
    if (tid < 64) {
        float2* xs2 = (float2*)smem;           // [128 t][64 p]
        float2 A = Lbar[nb * 64 + tid];
        float xr = 0.f, xi = 0.f;
        for (int t = 0; t < CHUNK; t++) {
            float2 v = xs2[t * 64 + tid];
            float nr = fmaf(A.x, xr, fmaf(-A.y, xi, v.x));
            float ni = fmaf(A.x, xi, fmaf(A.y, xr, v.y));
            xr = nr; xi = ni;
            xs2[t * 64 + tid] = make_float2(xr, xi);
        }
        carries[(size_t)g * P_SZ + nb * 64 + tid] = make_float2(xr, xi);
    }
    __syncthreads();
    const float4* xs4 = (const float4*)smem;   // [128][32] (re,im,re,im)
    #pragma unroll
    for (int it = 0; it < 16; it++) {
        int lin = tid + it * 256;              // 4096
        int row = lin >> 5;
        int c4  = lin & 31;
        float4 v = xs4[lin];
        ushort4 h4, l4;
        splitf(v.x, h4.x, l4.x);
        splitf(v.y, h4.y, l4.y);
        splitf(v.z, h4.z, l4.z);
        splitf(v.w, h4.w, l4.w);
        size_t o = (size_t)(m0 + row) * 1024 + n0 + c4 * 4;
        *(ushort4*)&Xc[o] = h4;
        *(ushort4*)&Xc[MK2 + o] = l4;
    }
}

__global__ void scanB_k(float2* __restrict__ carries,
                        const float2* __restrict__ AS) {
    int tid = blockIdx.x * blockDim.x + threadIdx.x;
    int p = tid & (P_SZ - 1);
    int b = tid / P_SZ;
    float2 A = AS[p];
    float cr = 0.f, ci = 0.f;
    for (int c = 0; c < NCH; c++) {
        int idx = (b * NCH + c) * P_SZ + p;
        float2 t = carries[idx];
        carries[idx] = make_float2(cr, ci);
        float nr = fmaf(A.x, cr, fmaf(-A.y, ci, t.x));
        float ni = fmaf(A.x, ci, fmaf(A.y, cr, t.y));
        cr = nr; ci = ni;
    }
}

// In-place carry fix-up on the interleaved X planes:
// x_global = x_local + Lbar^(t+1)*carry  (hi+lo reconstruct is exact to 2^-18)
__global__ __launch_bounds__(256) void xfix_k(unsigned short* __restrict__ Xc,
                                              const float2* __restrict__ PpowS,
                                              const float2* __restrict__ Lbar,
                                              const float2* __restrict__ carries) {
    int t = blockIdx.x * 256 + threadIdx.x;
    int pc = t & 255;                  // complex pair p0=2pc, p0+1 -> k' = 4pc..4pc+3
    int rb = t >> 8;                   // 8-row block
    int p0 = pc * 2;
    int m0 = rb * 8;
    int g = m0 >> 7;                   // chunk
    int r = (m0 & 127) >> 3;           // stepped-power row
    float4 cv = *(const float4*)&carries[(size_t)g * P_SZ + p0];
    float4 wv = *(const float4*)&PpowS[(size_t)r * P_SZ + p0];
    float4 lb = *(const float4*)&Lbar[p0];
    float d0r = wv.x * cv.x - wv.y * cv.y;
    float d0i = wv.x * cv.y + wv.y * cv.x;
    float d1r = wv.z * cv.z - wv.w * cv.w;
    float d1i = wv.z * cv.w + wv.w * cv.z;
    #pragma unroll
    for (int q = 0; q < 8; q++) {
        size_t o = (size_t)(m0 + q) * 1024 + (size_t)p0 * 2;
        ushort4 h = *(const ushort4*)&Xc[o];
        ushort4 l = *(const ushort4*)&Xc[MK2 + o];
        float xr0 = b2f(h.x) + b2f(l.x) + d0r;
        float xi0 = b2f(h.y) + b2f(l.y) + d0i;
        float xr1 = b2f(h.z) + b2f(l.z) + d1r;
        float xi1 = b2f(h.w) + b2f(l.w) + d1i;
        float t0r = d0r * lb.x - d0i * lb.y;
        float t0i = d0r * lb.y + d0i * lb.x;
        float t1r = d1r * lb.z - d1i * lb.w;
        float t1i = d1r * lb.w + d1i * lb.z;
        d0r = t0r; d0i = t0i; d1r = t1r; d1i = t1i;
        splitf(xr0, h.x, l.x);
        splitf(xi0, h.y, l.y);
        splitf(xr1, h.z, l.z);
        splitf(xi1, h.w, l.w);
        *(ushort4*)&Xc[o] = h;
        *(ushort4*)&Xc[MK2 + o] = l;
    }
}

// GEMM2: Y[m][h] = 2 * Xc[m][k'] * Cc[h][k'] over K'=1024 (re/im folded into K).
// Block 128x128, 4 waves of 64x64, 2-plane split. R3/R8-VERBATIM.
__global__ __launch_bounds__(256, 2) void gemm2_k(const unsigned short* __restrict__ Xc,
                                                  const unsigned short* __restrict__ Cc,
                                                  float* __restrict__ Y) {
    __shared__ __align__(16) char smem[40960];
    unsigned short* sAh = (unsigned short*)smem;
    unsigned short* sAl = sAh + 128 * LDSP;
    unsigned short* sBh = sAl + 128 * LDSP;
    unsigned short* sBl = sBh + 128 * LDSP;
    const int tid = threadIdx.x;
    int g, nb;
    deswizzle4(blockIdx.x, g, nb);
    const int m0 = g * 128;
    const int n0 = nb * 128;
    const int lane = tid & 63, wv = tid >> 6;
    const int wm = wv & 1, wn = wv >> 1;
    const int lr = lane & 15, kg = lane >> 4;

    f32x4 acc[4][4];
    #pragma unroll
    for (int i = 0; i < 4; i++)
        #pragma unroll
        for (int j = 0; j < 4; j++) acc[i][j] = (f32x4)0.0f;

    const int srow = tid >> 2, sc8 = tid & 3;
    const int so0 = srow * LDSP + sc8 * 8;
    const int so1 = (srow + 64) * LDSP + sc8 * 8;

    const unsigned short* gAh = Xc + (size_t)(m0 + srow) * 1024 + sc8 * 8;
    const unsigned short* gAl = gAh + MK2;
    const unsigned short* gBh = Cc + (size_t)(n0 + srow) * 1024 + sc8 * 8;
    const unsigned short* gBl = gBh + KW;
    const size_t rs = (size_t)64 * 1024;

    int4 ah0 = *(const int4*)gAh, ah1 = *(const int4*)(gAh + rs);
    int4 al0 = *(const int4*)gAl, al1 = *(const int4*)(gAl + rs);
    int4 bh0 = *(const int4*)gBh, bh1 = *(const int4*)(gBh + rs);
    int4 bl0 = *(const int4*)gBl, bl1 = *(const int4*)(gBl + rs);

    for (int k0 = 0; k0 < 1024; k0 += 32) {
        __syncthreads();
        *(int4*)&sAh[so0] = ah0; *(int4*)&sAh[so1] = ah1;
        *(int4*)&sAl[so0] = al0; *(int4*)&sAl[so1] = al1;
        *(int4*)&sBh[so0] = bh0; *(int4*)&sBh[so1] = bh1;
        *(int4*)&sBl[so0] = bl0; *(int4*)&sBl[so1] = bl1;
        __syncthreads();
        if (k0 + 32 < 1024) {
            gAh += 32; gAl += 32; gBh += 32; gBl += 32;
            ah0 = *(const int4*)gAh; ah1 = *(const int4*)(gAh + rs);
            al0 = *(const int4*)gAl; al1 = *(const int4*)(gAl + rs);
            bh0 = *(const int4*)gBh; bh1 = *(const int4*)(gBh + rs);
            bl0 = *(const int4*)gBl; bl1 = *(const int4*)(gBl + rs);
        }

        bf16x8 fah[4], fal[4], fbh[4], fbl[4];
        #pragma unroll
        for (int mi = 0; mi < 4; mi++) {
            int off = (wm * 64 + mi * 16 + lr) * LDSP + kg * 8;
            fah[mi] = *(const bf16x8*)&sAh[off];
            fal[mi] = *(const bf16x8*)&sAl[off];
        }
        #pragma unroll
        for (int nj = 0; nj < 4; nj++) {
            int off = (wn * 64 + nj * 16 + lr) * LDSP + kg * 8;
            fbh[nj] = *(const bf16x8*)&sBh[off];
            fbl[nj] = *(const bf16x8*)&sBl[off];
        }
        #pragma unroll
        for (int mi = 0; mi < 4; mi++)
            #pragma unroll
            for (int nj = 0; nj < 4; nj++) {
                acc[mi][nj] = __builtin_amdgcn_mfma_f32_16x16x32_bf16(fah[mi], fbh[nj], acc[mi][nj], 0, 0, 0);
                acc[mi][nj] = __builtin_amdgcn_mfma_f32_16x16x32_bf16(fah[mi], fbl[nj], acc[mi][nj], 0, 0, 0);
                acc[mi][nj] = __builtin_amdgcn_mfma_f32_16x16x32_bf16(fal[mi], fbh[nj], acc[mi][nj], 0, 0, 0);
            }
    }
    #pragma unroll
    for (int mi = 0; mi < 4; mi++)
        #pragma unroll
        for (int nj = 0; nj < 4; nj++)
            #pragma unroll
            for (int r = 0; r < 4; r++) {
                int m = m0 + wm * 64 + mi * 16 + kg * 4 + r;
                int h = n0 + wn * 64 + nj * 16 + lr;
                Y[(size_t)m * H_SZ + h] = 2.0f * acc[mi][nj][r];
            }
}

extern "C" void kernel_launch(void* const* d_in, const int* in_sizes, int n_in,
                              void* d_out, int out_size, void* d_ws, size_t ws_size,
                              hipStream_t stream) {
    const float* lam_re   = (const float*)d_in[0];
    const float* lam_im   = (const float*)d_in[1];
    const float* Bre      = (const float*)d_in[2];
    const float* Bim      = (const float*)d_in[3];
    const float* Cre      = (const float*)d_in[4];
    const float* Cim      = (const float*)d_in[5];
    const float* log_step = (const float*)d_in[6];
    const float* U        = (const float*)d_in[7];
    float* Y = (float*)d_out;

    char* ws = (char*)d_ws;
    unsigned short* Xc = (unsigned short*)ws;                   // 134.2 MB (2 planes, k'-interleaved)
    ws += 2 * MK2 * sizeof(unsigned short);
    unsigned short* Wc = (unsigned short*)ws;                   // 2 MB
    ws += 2 * KW * sizeof(unsigned short);
    unsigned short* Cc = (unsigned short*)ws;                   // 2 MB
    ws += 2 * KW * sizeof(unsigned short);
    float2* Lbar = (float2*)ws;  ws += P_SZ * sizeof(float2);
    float2* AS   = (float2*)ws;  ws += P_SZ * sizeof(float2);
    float2* scale = (float2*)ws; ws += P_SZ * sizeof(float2);
    float2* carries = (float2*)ws;                              // 1 MB
    ws += (size_t)B_SZ * NCH * P_SZ * sizeof(float2);
    float2* PpowS = (float2*)ws;                                // 64 KB

    precompute_k<<<dim3((P_SZ + 255) / 256), dim3(256), 0, stream>>>(
        lam_re, lam_im, log_step, Lbar, AS, scale);
    ppows_k<<<dim3((16 * P_SZ) / 256), dim3(256), 0, stream>>>(Lbar, PpowS);
    bbar_k<<<dim3(PH / 256), dim3(256), 0, stream>>>(Bre, Bim, scale, Wc);
    csplit_k<<<dim3(PH / 256), dim3(256), 0, stream>>>(Cre, Cim, Cc);
    gemm1_k<<<dim3((M_SZ / 128) * (1024 / 128)), dim3(256), 0, stream>>>(U, Wc, Lbar, Xc, carries);
    scanB_k<<<dim3((B_SZ * P_SZ) / 256), dim3(256), 0, stream>>>(carries, AS);
    xfix_k<<<dim3((int)(MK2 / 32 / 256)), dim3(256), 0, stream>>>(Xc, PpowS, Lbar, carries);
    gemm2_k<<<dim3((M_SZ / 128) * (H_SZ / 128)), dim3(256), 0, stream>>>(Xc, Cc, Y);
}